// Round 1
// baseline (623.547 us; speedup 1.0000x reference)
//
#include <hip/hip_runtime.h>
#include <stdint.h>

// ---------------------------------------------------------------------------
// SpeechResModel forward: conv(1->32,k(20,5),s(8,2))+ReLU -> 2-layer LSTM(576->128->128)
// -> additive attention pooling over T=100 -> FC 128->64->12.
// B=512, T=100, W'=18, LSTM_IN=576, HID=128, GATES=512.
// Strategy: bf16 MFMA for all big GEMMs; MFMA-based batch-parallel LSTM scan
// with weights resident in VGPR B-fragments; Xp stored [t][gate][batch] bf16.
// ---------------------------------------------------------------------------

#define T_STEPS 100
#define BATCH   512
#define HIDD    128
#define GATES   512
#define LSTMIN  576
#define HIMG    812
#define WIMG    40

typedef __attribute__((ext_vector_type(8))) short bf16x8;
typedef __attribute__((ext_vector_type(4))) float f32x4;

__device__ inline unsigned short f2bf(float f) {
  unsigned u = __float_as_uint(f);
  unsigned r = (u + 0x7fffu + ((u >> 16) & 1u)) >> 16;
  return (unsigned short)r;
}
__device__ inline float bf2f(unsigned short b) {
  return __uint_as_float(((unsigned)b) << 16);
}
__device__ inline float fsigm(float x) {
  float e = __expf(-x);
  return __builtin_amdgcn_rcpf(1.f + e);
}
__device__ inline float ftanh(float x) {
  float e = __expf(2.f * x);
  return (e - 1.f) * __builtin_amdgcn_rcpf(e + 1.f);
}
// LDS-only barrier: does NOT drain vmcnt, so in-flight global prefetches
// survive across it (unlike __syncthreads, which emits vmcnt(0)).
__device__ inline void lds_barrier() {
  asm volatile("s_waitcnt lgkmcnt(0)" ::: "memory");
  __builtin_amdgcn_s_barrier();
}

// ---------------------------------------------------------------------------
// K0: weight prep — bf16 casts, W_att transpose, conv weight k-major transpose,
// bias sums. Re-run every launch (ws is re-poisoned by the harness).
// ---------------------------------------------------------------------------
__global__ void prep_kernel(const float* __restrict__ Wih0, const float* __restrict__ Whh0,
                            const float* __restrict__ Wih1, const float* __restrict__ Whh1,
                            const float* __restrict__ Watt, const float* __restrict__ convw,
                            const float* __restrict__ bih0, const float* __restrict__ bhh0,
                            const float* __restrict__ bih1, const float* __restrict__ bhh1,
                            unsigned short* __restrict__ wih0b, unsigned short* __restrict__ whh0b,
                            unsigned short* __restrict__ wih1b, unsigned short* __restrict__ whh1b,
                            unsigned short* __restrict__ wattb, float* __restrict__ convwt,
                            float* __restrict__ bias0, float* __restrict__ bias1) {
  int tid = blockIdx.x * blockDim.x + threadIdx.x;
  int stride = gridDim.x * blockDim.x;
  for (int i = tid; i < GATES * LSTMIN; i += stride) wih0b[i] = f2bf(Wih0[i]);
  for (int i = tid; i < GATES * HIDD; i += stride) whh0b[i] = f2bf(Whh0[i]);
  for (int i = tid; i < GATES * HIDD; i += stride) wih1b[i] = f2bf(Wih1[i]);
  for (int i = tid; i < GATES * HIDD; i += stride) whh1b[i] = f2bf(Whh1[i]);
  // wattb[j][k] = Watt[k][j]  (einsum 'tbh,hk->tbk' -> B^T layout)
  for (int i = tid; i < HIDD * HIDD; i += stride) {
    int j = i >> 7, k = i & 127;
    wattb[i] = f2bf(Watt[k * HIDD + j]);
  }
  // convwt[k][c] = convw[c][k], k = kh*5+kw (k-major for SGPR streaming)
  for (int i = tid; i < 3200; i += stride) {
    int k = i >> 5, c = i & 31;
    convwt[i] = convw[c * 100 + k];
  }
  for (int i = tid; i < GATES; i += stride) bias0[i] = bih0[i] + bhh0[i];
  for (int i = tid; i < GATES; i += stride) bias1[i] = bih1[i] + bhh1[i];
}

// ---------------------------------------------------------------------------
// K1: conv + ReLU + transpose to seq[t][b][w'*32+c] (bf16).
// Block = (b, t-chunk of 25). Image strip in LDS; weights stream through
// SGPRs (uniform addresses) -> 1 LDS read per 32 FMAs.
// ---------------------------------------------------------------------------
__global__ __launch_bounds__(256) void conv_kernel(const float* __restrict__ x,
                                                   const float* __restrict__ convwt,
                                                   const float* __restrict__ convb,
                                                   unsigned short* __restrict__ seq) {
  __shared__ __align__(16) float img[212 * WIMG];
  const int b = blockIdx.x;
  const int chunk = blockIdx.y;       // 0..3
  const int t0 = chunk * 25;
  const int row0 = 8 * t0;            // rows row0 .. row0+211 (max 811)
  const float4* src = (const float4*)(x + (size_t)b * (HIMG * WIMG) + (size_t)row0 * WIMG);
  float4* dst = (float4*)img;
  for (int i = threadIdx.x; i < 212 * WIMG / 4; i += 256) dst[i] = src[i];
  __syncthreads();
  for (int p = threadIdx.x; p < 450; p += 256) {
    int tl = p / 18, wp = p % 18;
    int t = t0 + tl;
    float acc[32];
#pragma unroll
    for (int c = 0; c < 32; ++c) acc[c] = 0.f;
    const float* ibase = img + (8 * tl) * WIMG + 2 * wp;
#pragma unroll 2
    for (int kh = 0; kh < 20; ++kh) {
#pragma unroll
      for (int kw = 0; kw < 5; ++kw) {
        float iv = ibase[kh * WIMG + kw];
        const float* wk = convwt + (kh * 5 + kw) * 32;  // uniform -> s_load
#pragma unroll
        for (int c = 0; c < 32; ++c) acc[c] = fmaf(iv, wk[c], acc[c]);
      }
    }
    unsigned short* o = seq + ((size_t)(t * BATCH + b)) * LSTMIN + wp * 32;
#pragma unroll
    for (int c = 0; c < 32; ++c) {
      float v = acc[c] + convb[c];
      o[c] = f2bf(v > 0.f ? v : 0.f);
    }
  }
}

// ---------------------------------------------------------------------------
// K2: bf16 MFMA GEMM (m97 structure): C[m][n] = sum_k A[m][k]*Bw[n][k] + bias[n]
// Output stored TRANSPOSED per timestep: Xp[t][n][b] bf16 (t = m>>9, b = m&511)
// so the scan reads gate-inits contiguously in batch.
// 128x128 tile, BK=32, global_load_lds(16B), XOR-swizzled LDS k-groups.
// ---------------------------------------------------------------------------
template <int KDIM>
__global__ __launch_bounds__(256) void gemm_xp_kernel(const unsigned short* __restrict__ A,
                                                      const unsigned short* __restrict__ Bw,
                                                      const float* __restrict__ bias,
                                                      unsigned short* __restrict__ Xp) {
  __shared__ __align__(16) unsigned short As[128 * 32];
  __shared__ __align__(16) unsigned short Bs[128 * 32];
  const int tid = threadIdx.x;
  const int lane = tid & 63;
  const int w = tid >> 6;
  const int col16 = lane & 15;
  const int q = lane >> 4;
  const int n0 = blockIdx.x * 128;
  const int m0 = blockIdx.y * 128;
  const int wm = (w & 1) * 64;
  const int wn = (w >> 1) * 64;
  f32x4 acc[4][4] = {};
  const int r = tid >> 2;
  const int sw = ((tid & 3) ^ (r & 3)) * 8;           // swizzled k-group
  const unsigned wslot = (unsigned)w * 512;
  const unsigned short* ga = A + (size_t)(m0 + r) * KDIM + sw;
  const unsigned short* gb = Bw + (size_t)(n0 + r) * KDIM + sw;
  for (int k0 = 0; k0 < KDIM; k0 += 32) {
    __syncthreads();
    __builtin_amdgcn_global_load_lds((const __attribute__((address_space(1))) void*)(ga + k0),
                                     (__attribute__((address_space(3))) void*)(As + wslot), 16, 0, 0);
    __builtin_amdgcn_global_load_lds((const __attribute__((address_space(1))) void*)(ga + k0 + (size_t)64 * KDIM),
                                     (__attribute__((address_space(3))) void*)(As + wslot + 2048), 16, 0, 0);
    __builtin_amdgcn_global_load_lds((const __attribute__((address_space(1))) void*)(gb + k0),
                                     (__attribute__((address_space(3))) void*)(Bs + wslot), 16, 0, 0);
    __builtin_amdgcn_global_load_lds((const __attribute__((address_space(1))) void*)(gb + k0 + (size_t)64 * KDIM),
                                     (__attribute__((address_space(3))) void*)(Bs + wslot + 2048), 16, 0, 0);
    __syncthreads();  // drains vmcnt(0): LDS tiles valid
    bf16x8 af[4], bv[4];
#pragma unroll
    for (int i = 0; i < 4; ++i) {
      int ra = wm + i * 16 + col16;
      af[i] = *(const bf16x8*)(As + ra * 32 + ((q ^ (ra & 3)) * 8));
      int rb2 = wn + i * 16 + col16;
      bv[i] = *(const bf16x8*)(Bs + rb2 * 32 + ((q ^ (rb2 & 3)) * 8));
    }
#pragma unroll
    for (int i = 0; i < 4; ++i)
#pragma unroll
      for (int j = 0; j < 4; ++j)
        acc[i][j] = __builtin_amdgcn_mfma_f32_16x16x32_bf16(af[i], bv[j], acc[i][j], 0, 0, 0);
  }
  // epilogue: +bias, bf16, store transposed [t][n][b] (4 consecutive b -> 8B store)
#pragma unroll
  for (int ct = 0; ct < 4; ++ct) {
    int n = n0 + wn + ct * 16 + col16;
    float bvv = bias[n];
#pragma unroll
    for (int rt = 0; rt < 4; ++rt) {
      int m = m0 + wm + rt * 16 + q * 4;  // rows m..m+3, all same t (128 | 512)
      int t = m >> 9;
      int bb = m & 511;
      ushort4 u;
      u.x = f2bf(acc[rt][ct][0] + bvv);
      u.y = f2bf(acc[rt][ct][1] + bvv);
      u.z = f2bf(acc[rt][ct][2] + bvv);
      u.w = f2bf(acc[rt][ct][3] + bvv);
      *(ushort4*)(Xp + ((size_t)(t * GATES + n)) * BATCH + bb) = u;
    }
  }
}

// ---------------------------------------------------------------------------
// K3: LSTM scan. 32 blocks x 16 batch rows, 4 waves. Whh resident in VGPR
// B-fragments (gate-aligned so each lane holds i,f,g,o of the same cell).
// h round-trips through padded LDS; c stays in registers. Xp prefetched
// distance-2 into a 4-slot register pipeline (t&3 const under unroll 4).
// ---------------------------------------------------------------------------
__global__ __launch_bounds__(256, 1) void scan_kernel(const unsigned short* __restrict__ Xp,
                                                      const unsigned short* __restrict__ Whh,
                                                      unsigned short* __restrict__ hout) {
  __shared__ __align__(16) unsigned short hlds[16 * 136];  // padded stride 136
  const int tid = threadIdx.x;
  const int lane = tid & 63;
  const int w = tid >> 6;
  const int col16 = lane & 15;
  const int q = lane >> 4;
  const int rb = blockIdx.x * 16;

  // B-fragments: ntile nt -> gate (nt>>1), half (nt&1): col = gate*128 + w*32 + half*16 + col16
  bf16x8 bfrag[8][4];
  const unsigned short* xpb[8];
#pragma unroll
  for (int nt = 0; nt < 8; ++nt) {
    int cn = (nt >> 1) * HIDD + w * 32 + (nt & 1) * 16 + col16;
#pragma unroll
    for (int ks = 0; ks < 4; ++ks)
      bfrag[nt][ks] = *(const bf16x8*)(Whh + (size_t)cn * HIDD + ks * 32 + q * 8);
    xpb[nt] = Xp + (size_t)cn * BATCH + rb + q * 4;
  }
  for (int i = tid; i < 16 * 136; i += 256) hlds[i] = 0;
  float cst[8] = {0.f, 0.f, 0.f, 0.f, 0.f, 0.f, 0.f, 0.f};
  uint2 xb[4][8];
#pragma unroll
  for (int nt = 0; nt < 8; ++nt) xb[0][nt] = *(const uint2*)(xpb[nt]);
#pragma unroll
  for (int nt = 0; nt < 8; ++nt) xb[1][nt] = *(const uint2*)(xpb[nt] + GATES * BATCH);
  __syncthreads();

#pragma unroll 4
  for (int t = 0; t < T_STEPS; ++t) {
    if (t + 2 < T_STEPS) {
      int s2 = (t + 2) & 3;
#pragma unroll
      for (int nt = 0; nt < 8; ++nt)
        xb[s2][nt] = *(const uint2*)(xpb[nt] + (size_t)(t + 2) * (GATES * BATCH));
    }
    bf16x8 af[4];
#pragma unroll
    for (int ks = 0; ks < 4; ++ks)
      af[ks] = *(const bf16x8*)(hlds + col16 * 136 + ks * 32 + q * 8);
    f32x4 acc[8];
    const int s = t & 3;
#pragma unroll
    for (int nt = 0; nt < 8; ++nt) {
      uint2 xv = xb[s][nt];
      acc[nt][0] = __uint_as_float(xv.x << 16);
      acc[nt][1] = __uint_as_float(xv.x & 0xffff0000u);
      acc[nt][2] = __uint_as_float(xv.y << 16);
      acc[nt][3] = __uint_as_float(xv.y & 0xffff0000u);
    }
#pragma unroll
    for (int ks = 0; ks < 4; ++ks)
#pragma unroll
      for (int nt = 0; nt < 8; ++nt)
        acc[nt] = __builtin_amdgcn_mfma_f32_16x16x32_bf16(af[ks], bfrag[nt][ks], acc[nt], 0, 0, 0);
    unsigned short hv[8];
#pragma unroll
    for (int g2 = 0; g2 < 2; ++g2) {
#pragma unroll
      for (int rr = 0; rr < 4; ++rr) {
        int idx = g2 * 4 + rr;
        float pi = acc[0 + g2][rr], pf = acc[2 + g2][rr];
        float pg = acc[4 + g2][rr], po = acc[6 + g2][rr];
        float cc = fsigm(pf) * cst[idx] + fsigm(pi) * ftanh(pg);
        cst[idx] = cc;
        hv[idx] = f2bf(fsigm(po) * ftanh(cc));
      }
    }
    lds_barrier();  // all waves done reading hlds
    size_t hob = ((size_t)t * BATCH + rb) * HIDD;
#pragma unroll
    for (int g2 = 0; g2 < 2; ++g2) {
      int hc = w * 32 + g2 * 16 + col16;
#pragma unroll
      for (int rr = 0; rr < 4; ++rr) {
        int rowl = q * 4 + rr;
        unsigned short v = hv[g2 * 4 + rr];
        hlds[rowl * 136 + hc] = v;
        hout[hob + (size_t)rowl * HIDD + hc] = v;
      }
    }
    lds_barrier();  // writes visible before next step's reads
  }
}

// ---------------------------------------------------------------------------
// K4: attention scores: s[m] = v . tanh(h2[m] @ W_att + b_att). Same GEMM core
// (K=128, single n-tile), reduction epilogue.
// ---------------------------------------------------------------------------
__global__ __launch_bounds__(256) void gemm_att_kernel(const unsigned short* __restrict__ A,
                                                       const unsigned short* __restrict__ Bw,
                                                       const float* __restrict__ b_att,
                                                       const float* __restrict__ v_att,
                                                       float* __restrict__ scores) {
  __shared__ __align__(16) unsigned short As[128 * 32];
  __shared__ __align__(16) unsigned short Bs[128 * 32];
  __shared__ float s_red[128];
  const int tid = threadIdx.x;
  const int lane = tid & 63;
  const int w = tid >> 6;
  const int col16 = lane & 15;
  const int q = lane >> 4;
  const int m0 = blockIdx.y * 128;
  const int wm = (w & 1) * 64;
  const int wn = (w >> 1) * 64;
  f32x4 acc[4][4] = {};
  const int r = tid >> 2;
  const int sw = ((tid & 3) ^ (r & 3)) * 8;
  const unsigned wslot = (unsigned)w * 512;
  const unsigned short* ga = A + (size_t)(m0 + r) * HIDD + sw;
  const unsigned short* gb = Bw + (size_t)r * HIDD + sw;
  for (int k0 = 0; k0 < HIDD; k0 += 32) {
    __syncthreads();
    __builtin_amdgcn_global_load_lds((const __attribute__((address_space(1))) void*)(ga + k0),
                                     (__attribute__((address_space(3))) void*)(As + wslot), 16, 0, 0);
    __builtin_amdgcn_global_load_lds((const __attribute__((address_space(1))) void*)(ga + k0 + (size_t)64 * HIDD),
                                     (__attribute__((address_space(3))) void*)(As + wslot + 2048), 16, 0, 0);
    __builtin_amdgcn_global_load_lds((const __attribute__((address_space(1))) void*)(gb + k0),
                                     (__attribute__((address_space(3))) void*)(Bs + wslot), 16, 0, 0);
    __builtin_amdgcn_global_load_lds((const __attribute__((address_space(1))) void*)(gb + k0 + (size_t)64 * HIDD),
                                     (__attribute__((address_space(3))) void*)(Bs + wslot + 2048), 16, 0, 0);
    __syncthreads();
    bf16x8 af[4], bv[4];
#pragma unroll
    for (int i = 0; i < 4; ++i) {
      int ra = wm + i * 16 + col16;
      af[i] = *(const bf16x8*)(As + ra * 32 + ((q ^ (ra & 3)) * 8));
      int rb2 = wn + i * 16 + col16;
      bv[i] = *(const bf16x8*)(Bs + rb2 * 32 + ((q ^ (rb2 & 3)) * 8));
    }
#pragma unroll
    for (int i = 0; i < 4; ++i)
#pragma unroll
      for (int j = 0; j < 4; ++j)
        acc[i][j] = __builtin_amdgcn_mfma_f32_16x16x32_bf16(af[i], bv[j], acc[i][j], 0, 0, 0);
  }
  if (tid < 128) s_red[tid] = 0.f;
  float rs[4][4];
#pragma unroll
  for (int rt = 0; rt < 4; ++rt)
#pragma unroll
    for (int rr = 0; rr < 4; ++rr) rs[rt][rr] = 0.f;
#pragma unroll
  for (int ct = 0; ct < 4; ++ct) {
    int n = wn + ct * 16 + col16;
    float bvv = b_att[n], vv = v_att[n];
#pragma unroll
    for (int rt = 0; rt < 4; ++rt)
#pragma unroll
      for (int rr = 0; rr < 4; ++rr) {
        float xv2 = acc[rt][ct][rr] + bvv;
        float e = __expf(2.f * xv2);
        rs[rt][rr] += vv * (e - 1.f) * __builtin_amdgcn_rcpf(e + 1.f);
      }
  }
#pragma unroll
  for (int off = 1; off < 16; off <<= 1)
#pragma unroll
    for (int rt = 0; rt < 4; ++rt)
#pragma unroll
      for (int rr = 0; rr < 4; ++rr) rs[rt][rr] += __shfl_xor(rs[rt][rr], off, 64);
  __syncthreads();
  if (col16 == 0) {
#pragma unroll
    for (int rt = 0; rt < 4; ++rt)
#pragma unroll
      for (int rr = 0; rr < 4; ++rr)
        atomicAdd(&s_red[wm + rt * 16 + q * 4 + rr], rs[rt][rr]);
  }
  __syncthreads();
  if (tid < 128) scores[m0 + tid] = s_red[tid];
}

// ---------------------------------------------------------------------------
// K5: per-batch softmax over T, attention pooling, FC 128->64->12.
// ---------------------------------------------------------------------------
__global__ __launch_bounds__(128) void final_kernel(const float* __restrict__ scores,
                                                    const unsigned short* __restrict__ h2,
                                                    const float* __restrict__ W1, const float* __restrict__ b1,
                                                    const float* __restrict__ W2, const float* __restrict__ b2,
                                                    float* __restrict__ out) {
  const int b = blockIdx.x;
  const int tid = threadIdx.x;
  __shared__ float wj[T_STEPS];
  __shared__ float red[128];
  __shared__ float pooled[128];
  __shared__ float hdn[64];
  float sv = (tid < T_STEPS) ? scores[tid * BATCH + b] : -1e30f;
  red[tid] = sv;
  __syncthreads();
#pragma unroll
  for (int off = 64; off > 0; off >>= 1) {
    if (tid < off) red[tid] = fmaxf(red[tid], red[tid + off]);
    __syncthreads();
  }
  float mx = red[0];
  __syncthreads();
  float ev = (tid < T_STEPS) ? __expf(sv - mx) : 0.f;
  red[tid] = ev;
  __syncthreads();
#pragma unroll
  for (int off = 64; off > 0; off >>= 1) {
    if (tid < off) red[tid] += red[tid + off];
    __syncthreads();
  }
  float inv = 1.0f / red[0];
  if (tid < T_STEPS) wj[tid] = ev * inv;
  __syncthreads();
  // pooled[h] = sum_t wj[t] * h2[t][b][h]
  float p = 0.f;
  for (int t = 0; t < T_STEPS; ++t)
    p += wj[t] * bf2f(h2[((size_t)(t * BATCH + b)) * HIDD + tid]);
  pooled[tid] = p;
  __syncthreads();
  if (tid < 64) {
    float a = b1[tid];
    for (int h = 0; h < 128; ++h) a = fmaf(W1[tid * 128 + h], pooled[h], a);
    hdn[tid] = a;
  }
  __syncthreads();
  if (tid < 12) {
    float a = b2[tid];
    for (int j = 0; j < 64; ++j) a = fmaf(W2[tid * 64 + j], hdn[j], a);
    out[b * 12 + tid] = a;
  }
}

// ---------------------------------------------------------------------------
extern "C" void kernel_launch(void* const* d_in, const int* in_sizes, int n_in,
                              void* d_out, int out_size, void* d_ws, size_t ws_size,
                              hipStream_t stream) {
  (void)in_sizes; (void)n_in; (void)out_size; (void)ws_size;
  const float* x      = (const float*)d_in[0];
  const float* conv_w = (const float*)d_in[1];
  const float* conv_b = (const float*)d_in[2];
  const float* Wih0   = (const float*)d_in[3];
  const float* Whh0   = (const float*)d_in[4];
  const float* bih0   = (const float*)d_in[5];
  const float* bhh0   = (const float*)d_in[6];
  const float* Wih1   = (const float*)d_in[7];
  const float* Whh1   = (const float*)d_in[8];
  const float* bih1   = (const float*)d_in[9];
  const float* bhh1   = (const float*)d_in[10];
  const float* W_att  = (const float*)d_in[11];
  const float* b_att  = (const float*)d_in[12];
  const float* v_att  = (const float*)d_in[13];
  const float* W1     = (const float*)d_in[14];
  const float* b1     = (const float*)d_in[15];
  const float* W2     = (const float*)d_in[16];
  const float* b2     = (const float*)d_in[17];

  char* ws = (char*)d_ws;
  size_t off = 0;
  auto carve = [&](size_t bytes) { char* p = ws + off; off += (bytes + 255) & ~(size_t)255; return p; };
  unsigned short* seq    = (unsigned short*)carve((size_t)T_STEPS * BATCH * LSTMIN * 2);  // 59.0 MB
  unsigned short* xp     = (unsigned short*)carve((size_t)T_STEPS * GATES * BATCH * 2);   // 52.4 MB (reused L0/L1)
  unsigned short* h1     = (unsigned short*)carve((size_t)T_STEPS * BATCH * HIDD * 2);    // 13.1 MB
  unsigned short* h2     = (unsigned short*)carve((size_t)T_STEPS * BATCH * HIDD * 2);    // 13.1 MB
  float*          scores = (float*)carve((size_t)T_STEPS * BATCH * 4);
  unsigned short* wih0b  = (unsigned short*)carve((size_t)GATES * LSTMIN * 2);
  unsigned short* whh0b  = (unsigned short*)carve((size_t)GATES * HIDD * 2);
  unsigned short* wih1b  = (unsigned short*)carve((size_t)GATES * HIDD * 2);
  unsigned short* whh1b  = (unsigned short*)carve((size_t)GATES * HIDD * 2);
  unsigned short* wattb  = (unsigned short*)carve((size_t)HIDD * HIDD * 2);
  float*          convwt = (float*)carve(3200 * 4);
  float*          bias0  = (float*)carve(GATES * 4);
  float*          bias1  = (float*)carve(GATES * 4);
  // total ~139 MB of ws

  prep_kernel<<<256, 256, 0, stream>>>(Wih0, Whh0, Wih1, Whh1, W_att, conv_w,
                                       bih0, bhh0, bih1, bhh1,
                                       wih0b, whh0b, wih1b, whh1b, wattb, convwt, bias0, bias1);
  conv_kernel<<<dim3(512, 4), 256, 0, stream>>>(x, convwt, conv_b, seq);
  gemm_xp_kernel<LSTMIN><<<dim3(4, 400), 256, 0, stream>>>(seq, wih0b, bias0, xp);
  scan_kernel<<<32, 256, 0, stream>>>(xp, whh0b, h1);
  gemm_xp_kernel<HIDD><<<dim3(4, 400), 256, 0, stream>>>(h1, wih1b, bias1, xp);
  scan_kernel<<<32, 256, 0, stream>>>(xp, whh1b, h2);
  gemm_att_kernel<<<dim3(1, 400), 256, 0, stream>>>(h2, wattb, b_att, v_att, scores);
  final_kernel<<<512, 128, 0, stream>>>(scores, h2, W1, b1, W2, b2, (float*)d_out);
}

// Round 2
// 508.666 us; speedup vs baseline: 1.2258x; 1.2258x over previous
//
#include <hip/hip_runtime.h>
#include <stdint.h>

// ---------------------------------------------------------------------------
// SpeechResModel forward: conv(1->32,k(20,5),s(8,2))+ReLU -> 2-layer LSTM(576->128->128)
// -> additive attention pooling over T=100 -> FC 128->64->12.
// B=512, T=100, W'=18, LSTM_IN=576, HID=128, GATES=512.
// R2: scan_kernel rewritten as 512-thread blocks (8 waves, 2/SIMD latency
// hiding), Xp stored in scan-native order (fully coalesced per-step loads),
// h stores coalesced via LDS round-trip.
// ---------------------------------------------------------------------------

#define T_STEPS 100
#define BATCH   512
#define HIDD    128
#define GATES   512
#define LSTMIN  576
#define HIMG    812
#define WIMG    40

typedef __attribute__((ext_vector_type(8))) short bf16x8;
typedef __attribute__((ext_vector_type(4))) float f32x4;

__device__ inline unsigned short f2bf(float f) {
  unsigned u = __float_as_uint(f);
  unsigned r = (u + 0x7fffu + ((u >> 16) & 1u)) >> 16;
  return (unsigned short)r;
}
__device__ inline float bf2f(unsigned short b) {
  return __uint_as_float(((unsigned)b) << 16);
}
__device__ inline float fsigm(float x) {
  float e = __expf(-x);
  return __builtin_amdgcn_rcpf(1.f + e);
}
__device__ inline float ftanh(float x) {
  float e = __expf(2.f * x);
  return (e - 1.f) * __builtin_amdgcn_rcpf(e + 1.f);
}
// LDS-only barrier: does NOT drain vmcnt, so in-flight global prefetches
// survive across it (unlike __syncthreads, which emits vmcnt(0)).
__device__ inline void lds_barrier() {
  asm volatile("s_waitcnt lgkmcnt(0)" ::: "memory");
  __builtin_amdgcn_s_barrier();
}

// ---------------------------------------------------------------------------
// K0: weight prep — bf16 casts, W_att transpose, conv weight k-major transpose,
// bias sums. Re-run every launch (ws is re-poisoned by the harness).
// ---------------------------------------------------------------------------
__global__ void prep_kernel(const float* __restrict__ Wih0, const float* __restrict__ Whh0,
                            const float* __restrict__ Wih1, const float* __restrict__ Whh1,
                            const float* __restrict__ Watt, const float* __restrict__ convw,
                            const float* __restrict__ bih0, const float* __restrict__ bhh0,
                            const float* __restrict__ bih1, const float* __restrict__ bhh1,
                            unsigned short* __restrict__ wih0b, unsigned short* __restrict__ whh0b,
                            unsigned short* __restrict__ wih1b, unsigned short* __restrict__ whh1b,
                            unsigned short* __restrict__ wattb, float* __restrict__ convwt,
                            float* __restrict__ bias0, float* __restrict__ bias1) {
  int tid = blockIdx.x * blockDim.x + threadIdx.x;
  int stride = gridDim.x * blockDim.x;
  for (int i = tid; i < GATES * LSTMIN; i += stride) wih0b[i] = f2bf(Wih0[i]);
  for (int i = tid; i < GATES * HIDD; i += stride) whh0b[i] = f2bf(Whh0[i]);
  for (int i = tid; i < GATES * HIDD; i += stride) wih1b[i] = f2bf(Wih1[i]);
  for (int i = tid; i < GATES * HIDD; i += stride) whh1b[i] = f2bf(Whh1[i]);
  // wattb[j][k] = Watt[k][j]  (einsum 'tbh,hk->tbk' -> B^T layout)
  for (int i = tid; i < HIDD * HIDD; i += stride) {
    int j = i >> 7, k = i & 127;
    wattb[i] = f2bf(Watt[k * HIDD + j]);
  }
  // convwt[k][c] = convw[c][k], k = kh*5+kw (k-major for SGPR streaming)
  for (int i = tid; i < 3200; i += stride) {
    int k = i >> 5, c = i & 31;
    convwt[i] = convw[c * 100 + k];
  }
  for (int i = tid; i < GATES; i += stride) bias0[i] = bih0[i] + bhh0[i];
  for (int i = tid; i < GATES; i += stride) bias1[i] = bih1[i] + bhh1[i];
}

// ---------------------------------------------------------------------------
// K1: conv + ReLU + transpose to seq[t][b][w'*32+c] (bf16).
// ---------------------------------------------------------------------------
__global__ __launch_bounds__(256) void conv_kernel(const float* __restrict__ x,
                                                   const float* __restrict__ convwt,
                                                   const float* __restrict__ convb,
                                                   unsigned short* __restrict__ seq) {
  __shared__ __align__(16) float img[212 * WIMG];
  const int b = blockIdx.x;
  const int chunk = blockIdx.y;       // 0..3
  const int t0 = chunk * 25;
  const int row0 = 8 * t0;            // rows row0 .. row0+211 (max 811)
  const float4* src = (const float4*)(x + (size_t)b * (HIMG * WIMG) + (size_t)row0 * WIMG);
  float4* dst = (float4*)img;
  for (int i = threadIdx.x; i < 212 * WIMG / 4; i += 256) dst[i] = src[i];
  __syncthreads();
  for (int p = threadIdx.x; p < 450; p += 256) {
    int tl = p / 18, wp = p % 18;
    int t = t0 + tl;
    float acc[32];
#pragma unroll
    for (int c = 0; c < 32; ++c) acc[c] = 0.f;
    const float* ibase = img + (8 * tl) * WIMG + 2 * wp;
#pragma unroll 2
    for (int kh = 0; kh < 20; ++kh) {
#pragma unroll
      for (int kw = 0; kw < 5; ++kw) {
        float iv = ibase[kh * WIMG + kw];
        const float* wk = convwt + (kh * 5 + kw) * 32;  // uniform -> s_load
#pragma unroll
        for (int c = 0; c < 32; ++c) acc[c] = fmaf(iv, wk[c], acc[c]);
      }
    }
    unsigned short* o = seq + ((size_t)(t * BATCH + b)) * LSTMIN + wp * 32;
#pragma unroll
    for (int c = 0; c < 32; ++c) {
      float v = acc[c] + convb[c];
      o[c] = f2bf(v > 0.f ? v : 0.f);
    }
  }
}

// ---------------------------------------------------------------------------
// K2: bf16 MFMA GEMM: C[m][n] = sum_k A[m][k]*Bw[n][k] + bias[n].
// Output stored in SCAN-NATIVE layout:
//   Xp2[((t*32+blk)*8 + w)*4 + nt][col16][r16]   (tiles of 256 shorts)
// where blk=bb>>4, r16=bb&15, w=(n>>4)&7, nt=n>>7, col16=n&15 — exactly the
// order scan waves read it, so each per-step wave load is one 512B segment.
// ---------------------------------------------------------------------------
template <int KDIM>
__global__ __launch_bounds__(256) void gemm_xp_kernel(const unsigned short* __restrict__ A,
                                                      const unsigned short* __restrict__ Bw,
                                                      const float* __restrict__ bias,
                                                      unsigned short* __restrict__ Xp) {
  __shared__ __align__(16) unsigned short As[128 * 32];
  __shared__ __align__(16) unsigned short Bs[128 * 32];
  const int tid = threadIdx.x;
  const int lane = tid & 63;
  const int w = tid >> 6;
  const int col16 = lane & 15;
  const int q = lane >> 4;
  const int n0 = blockIdx.x * 128;
  const int m0 = blockIdx.y * 128;
  const int wm = (w & 1) * 64;
  const int wn = (w >> 1) * 64;
  f32x4 acc[4][4] = {};
  const int r = tid >> 2;
  const int sw = ((tid & 3) ^ (r & 3)) * 8;           // swizzled k-group
  const unsigned wslot = (unsigned)w * 512;
  const unsigned short* ga = A + (size_t)(m0 + r) * KDIM + sw;
  const unsigned short* gb = Bw + (size_t)(n0 + r) * KDIM + sw;
  for (int k0 = 0; k0 < KDIM; k0 += 32) {
    __syncthreads();
    __builtin_amdgcn_global_load_lds((const __attribute__((address_space(1))) void*)(ga + k0),
                                     (__attribute__((address_space(3))) void*)(As + wslot), 16, 0, 0);
    __builtin_amdgcn_global_load_lds((const __attribute__((address_space(1))) void*)(ga + k0 + (size_t)64 * KDIM),
                                     (__attribute__((address_space(3))) void*)(As + wslot + 2048), 16, 0, 0);
    __builtin_amdgcn_global_load_lds((const __attribute__((address_space(1))) void*)(gb + k0),
                                     (__attribute__((address_space(3))) void*)(Bs + wslot), 16, 0, 0);
    __builtin_amdgcn_global_load_lds((const __attribute__((address_space(1))) void*)(gb + k0 + (size_t)64 * KDIM),
                                     (__attribute__((address_space(3))) void*)(Bs + wslot + 2048), 16, 0, 0);
    __syncthreads();  // drains vmcnt(0): LDS tiles valid
    bf16x8 af[4], bv[4];
#pragma unroll
    for (int i = 0; i < 4; ++i) {
      int ra = wm + i * 16 + col16;
      af[i] = *(const bf16x8*)(As + ra * 32 + ((q ^ (ra & 3)) * 8));
      int rb2 = wn + i * 16 + col16;
      bv[i] = *(const bf16x8*)(Bs + rb2 * 32 + ((q ^ (rb2 & 3)) * 8));
    }
#pragma unroll
    for (int i = 0; i < 4; ++i)
#pragma unroll
      for (int j = 0; j < 4; ++j)
        acc[i][j] = __builtin_amdgcn_mfma_f32_16x16x32_bf16(af[i], bv[j], acc[i][j], 0, 0, 0);
  }
  // epilogue: +bias, bf16, store in scan-native layout (8B stores)
#pragma unroll
  for (int ct = 0; ct < 4; ++ct) {
    int n = n0 + wn + ct * 16 + col16;
    float bvv = bias[n];
    int wS = (n >> 4) & 7;
    int ntS = n >> 7;
    int c16S = n & 15;
#pragma unroll
    for (int rt = 0; rt < 4; ++rt) {
      int m = m0 + wm + rt * 16 + q * 4;  // rows m..m+3, same t (128 | 512)
      int t = m >> 9;
      int bb = m & 511;
      int blk = bb >> 4;
      int r16 = bb & 15;
      ushort4 u;
      u.x = f2bf(acc[rt][ct][0] + bvv);
      u.y = f2bf(acc[rt][ct][1] + bvv);
      u.z = f2bf(acc[rt][ct][2] + bvv);
      u.w = f2bf(acc[rt][ct][3] + bvv);
      size_t tile = (((size_t)t * 32 + blk) * 8 + wS) * 4 + ntS;
      *(ushort4*)(Xp + tile * 256 + c16S * 16 + r16) = u;
    }
  }
}

// ---------------------------------------------------------------------------
// K3: LSTM scan. 32 blocks x 16 batch rows, 8 waves (2/SIMD). Wave w owns cell
// cols j = w*16+col16 for ALL 4 gates (nt = gate), so each lane combines
// i,f,g,o of its own cells. Whh resident in VGPR B-fragments (64 regs).
// h round-trips through padded LDS; c in registers; Xp prefetch distance-2
// into a 4-slot register pipeline; h stored coalesced via LDS read-back.
// ---------------------------------------------------------------------------
__global__ __launch_bounds__(512, 2) void scan_kernel(const unsigned short* __restrict__ Xp,
                                                      const unsigned short* __restrict__ Whh,
                                                      unsigned short* __restrict__ hout) {
  __shared__ __align__(16) unsigned short hlds[16 * 136];  // padded stride 136
  const int tid = threadIdx.x;
  const int lane = tid & 63;
  const int w = tid >> 6;          // 0..7
  const int col16 = lane & 15;
  const int q = lane >> 4;
  const int rb = blockIdx.x * 16;
  const int blk = blockIdx.x;

  // B-fragments: nt = gate, col cn = nt*128 + w*16 + col16
  bf16x8 bfrag[4][4];
  const unsigned short* xpb[4];
#pragma unroll
  for (int nt = 0; nt < 4; ++nt) {
    int cn = nt * HIDD + w * 16 + col16;
#pragma unroll
    for (int ks = 0; ks < 4; ++ks)
      bfrag[nt][ks] = *(const bf16x8*)(Whh + (size_t)cn * HIDD + ks * 32 + q * 8);
    // scan-native Xp: tile index ((t*32+blk)*8+w)*4+nt, lane offset col16*16+q*4
    xpb[nt] = Xp + (((size_t)blk * 8 + w) * 4 + nt) * 256 + col16 * 16 + q * 4;
  }
  for (int i = tid; i < 16 * 136; i += 512) hlds[i] = 0;
  float cst[4] = {0.f, 0.f, 0.f, 0.f};
  uint2 xb[4][4];
#pragma unroll
  for (int nt = 0; nt < 4; ++nt) xb[0][nt] = *(const uint2*)(xpb[nt]);
#pragma unroll
  for (int nt = 0; nt < 4; ++nt) xb[1][nt] = *(const uint2*)(xpb[nt] + GATES * BATCH);
  __syncthreads();

  const int srow = tid >> 5;           // 0..15 (h store read-back row)
  const int scol = (tid & 31) * 4;     // 0..124

#pragma unroll 4
  for (int t = 0; t < T_STEPS; ++t) {
    if (t + 2 < T_STEPS) {
      int s2 = (t + 2) & 3;
#pragma unroll
      for (int nt = 0; nt < 4; ++nt)
        xb[s2][nt] = *(const uint2*)(xpb[nt] + (size_t)(t + 2) * (GATES * BATCH));
    }
    bf16x8 af[4];
#pragma unroll
    for (int ks = 0; ks < 4; ++ks)
      af[ks] = *(const bf16x8*)(hlds + col16 * 136 + ks * 32 + q * 8);
    f32x4 acc[4];
    const int s = t & 3;
#pragma unroll
    for (int nt = 0; nt < 4; ++nt) {
      uint2 xv = xb[s][nt];
      acc[nt][0] = __uint_as_float(xv.x << 16);
      acc[nt][1] = __uint_as_float(xv.x & 0xffff0000u);
      acc[nt][2] = __uint_as_float(xv.y << 16);
      acc[nt][3] = __uint_as_float(xv.y & 0xffff0000u);
    }
#pragma unroll
    for (int ks = 0; ks < 4; ++ks)
#pragma unroll
      for (int nt = 0; nt < 4; ++nt)
        acc[nt] = __builtin_amdgcn_mfma_f32_16x16x32_bf16(af[ks], bfrag[nt][ks], acc[nt], 0, 0, 0);
    unsigned short hv[4];
#pragma unroll
    for (int rr = 0; rr < 4; ++rr) {
      float pi = acc[0][rr], pf = acc[1][rr];
      float pg = acc[2][rr], po = acc[3][rr];
      float cc = fsigm(pf) * cst[rr] + fsigm(pi) * ftanh(pg);
      cst[rr] = cc;
      hv[rr] = f2bf(fsigm(po) * ftanh(cc));
    }
    lds_barrier();  // all reads of h(t-1) (af + store read-back) complete
    {
      int hc = w * 16 + col16;
#pragma unroll
      for (int rr = 0; rr < 4; ++rr)
        hlds[(q * 4 + rr) * 136 + hc] = hv[rr];
    }
    lds_barrier();  // h(t) visible
    // coalesced h(t) store: each thread 8B
    ushort4 hx = *(const ushort4*)(hlds + srow * 136 + scol);
    *(ushort4*)(hout + ((size_t)(t * BATCH) + rb + srow) * HIDD + scol) = hx;
  }
}

// ---------------------------------------------------------------------------
// K4: attention scores: s[m] = v . tanh(h2[m] @ W_att + b_att).
// ---------------------------------------------------------------------------
__global__ __launch_bounds__(256) void gemm_att_kernel(const unsigned short* __restrict__ A,
                                                       const unsigned short* __restrict__ Bw,
                                                       const float* __restrict__ b_att,
                                                       const float* __restrict__ v_att,
                                                       float* __restrict__ scores) {
  __shared__ __align__(16) unsigned short As[128 * 32];
  __shared__ __align__(16) unsigned short Bs[128 * 32];
  __shared__ float s_red[128];
  const int tid = threadIdx.x;
  const int lane = tid & 63;
  const int w = tid >> 6;
  const int col16 = lane & 15;
  const int q = lane >> 4;
  const int m0 = blockIdx.y * 128;
  const int wm = (w & 1) * 64;
  const int wn = (w >> 1) * 64;
  f32x4 acc[4][4] = {};
  const int r = tid >> 2;
  const int sw = ((tid & 3) ^ (r & 3)) * 8;
  const unsigned wslot = (unsigned)w * 512;
  const unsigned short* ga = A + (size_t)(m0 + r) * HIDD + sw;
  const unsigned short* gb = Bw + (size_t)r * HIDD + sw;
  for (int k0 = 0; k0 < HIDD; k0 += 32) {
    __syncthreads();
    __builtin_amdgcn_global_load_lds((const __attribute__((address_space(1))) void*)(ga + k0),
                                     (__attribute__((address_space(3))) void*)(As + wslot), 16, 0, 0);
    __builtin_amdgcn_global_load_lds((const __attribute__((address_space(1))) void*)(ga + k0 + (size_t)64 * HIDD),
                                     (__attribute__((address_space(3))) void*)(As + wslot + 2048), 16, 0, 0);
    __builtin_amdgcn_global_load_lds((const __attribute__((address_space(1))) void*)(gb + k0),
                                     (__attribute__((address_space(3))) void*)(Bs + wslot), 16, 0, 0);
    __builtin_amdgcn_global_load_lds((const __attribute__((address_space(1))) void*)(gb + k0 + (size_t)64 * HIDD),
                                     (__attribute__((address_space(3))) void*)(Bs + wslot + 2048), 16, 0, 0);
    __syncthreads();
    bf16x8 af[4], bv[4];
#pragma unroll
    for (int i = 0; i < 4; ++i) {
      int ra = wm + i * 16 + col16;
      af[i] = *(const bf16x8*)(As + ra * 32 + ((q ^ (ra & 3)) * 8));
      int rb2 = wn + i * 16 + col16;
      bv[i] = *(const bf16x8*)(Bs + rb2 * 32 + ((q ^ (rb2 & 3)) * 8));
    }
#pragma unroll
    for (int i = 0; i < 4; ++i)
#pragma unroll
      for (int j = 0; j < 4; ++j)
        acc[i][j] = __builtin_amdgcn_mfma_f32_16x16x32_bf16(af[i], bv[j], acc[i][j], 0, 0, 0);
  }
  if (tid < 128) s_red[tid] = 0.f;
  float rs[4][4];
#pragma unroll
  for (int rt = 0; rt < 4; ++rt)
#pragma unroll
    for (int rr = 0; rr < 4; ++rr) rs[rt][rr] = 0.f;
#pragma unroll
  for (int ct = 0; ct < 4; ++ct) {
    int n = wn + ct * 16 + col16;
    float bvv = b_att[n], vv = v_att[n];
#pragma unroll
    for (int rt = 0; rt < 4; ++rt)
#pragma unroll
      for (int rr = 0; rr < 4; ++rr) {
        float xv2 = acc[rt][ct][rr] + bvv;
        float e = __expf(2.f * xv2);
        rs[rt][rr] += vv * (e - 1.f) * __builtin_amdgcn_rcpf(e + 1.f);
      }
  }
#pragma unroll
  for (int off = 1; off < 16; off <<= 1)
#pragma unroll
    for (int rt = 0; rt < 4; ++rt)
#pragma unroll
      for (int rr = 0; rr < 4; ++rr) rs[rt][rr] += __shfl_xor(rs[rt][rr], off, 64);
  __syncthreads();
  if (col16 == 0) {
#pragma unroll
    for (int rt = 0; rt < 4; ++rt)
#pragma unroll
      for (int rr = 0; rr < 4; ++rr)
        atomicAdd(&s_red[wm + rt * 16 + q * 4 + rr], rs[rt][rr]);
  }
  __syncthreads();
  if (tid < 128) scores[m0 + tid] = s_red[tid];
}

// ---------------------------------------------------------------------------
// K5: per-batch softmax over T, attention pooling, FC 128->64->12.
// ---------------------------------------------------------------------------
__global__ __launch_bounds__(128) void final_kernel(const float* __restrict__ scores,
                                                    const unsigned short* __restrict__ h2,
                                                    const float* __restrict__ W1, const float* __restrict__ b1,
                                                    const float* __restrict__ W2, const float* __restrict__ b2,
                                                    float* __restrict__ out) {
  const int b = blockIdx.x;
  const int tid = threadIdx.x;
  __shared__ float wj[T_STEPS];
  __shared__ float red[128];
  __shared__ float pooled[128];
  __shared__ float hdn[64];
  float sv = (tid < T_STEPS) ? scores[tid * BATCH + b] : -1e30f;
  red[tid] = sv;
  __syncthreads();
#pragma unroll
  for (int off = 64; off > 0; off >>= 1) {
    if (tid < off) red[tid] = fmaxf(red[tid], red[tid + off]);
    __syncthreads();
  }
  float mx = red[0];
  __syncthreads();
  float ev = (tid < T_STEPS) ? __expf(sv - mx) : 0.f;
  red[tid] = ev;
  __syncthreads();
#pragma unroll
  for (int off = 64; off > 0; off >>= 1) {
    if (tid < off) red[tid] += red[tid + off];
    __syncthreads();
  }
  float inv = 1.0f / red[0];
  if (tid < T_STEPS) wj[tid] = ev * inv;
  __syncthreads();
  float p = 0.f;
  for (int t = 0; t < T_STEPS; ++t)
    p += wj[t] * bf2f(h2[((size_t)(t * BATCH + b)) * HIDD + tid]);
  pooled[tid] = p;
  __syncthreads();
  if (tid < 64) {
    float a = b1[tid];
    for (int h = 0; h < 128; ++h) a = fmaf(W1[tid * 128 + h], pooled[h], a);
    hdn[tid] = a;
  }
  __syncthreads();
  if (tid < 12) {
    float a = b2[tid];
    for (int j = 0; j < 64; ++j) a = fmaf(W2[tid * 64 + j], hdn[j], a);
    out[b * 12 + tid] = a;
  }
}

// ---------------------------------------------------------------------------
extern "C" void kernel_launch(void* const* d_in, const int* in_sizes, int n_in,
                              void* d_out, int out_size, void* d_ws, size_t ws_size,
                              hipStream_t stream) {
  (void)in_sizes; (void)n_in; (void)out_size; (void)ws_size;
  const float* x      = (const float*)d_in[0];
  const float* conv_w = (const float*)d_in[1];
  const float* conv_b = (const float*)d_in[2];
  const float* Wih0   = (const float*)d_in[3];
  const float* Whh0   = (const float*)d_in[4];
  const float* bih0   = (const float*)d_in[5];
  const float* bhh0   = (const float*)d_in[6];
  const float* Wih1   = (const float*)d_in[7];
  const float* Whh1   = (const float*)d_in[8];
  const float* bih1   = (const float*)d_in[9];
  const float* bhh1   = (const float*)d_in[10];
  const float* W_att  = (const float*)d_in[11];
  const float* b_att  = (const float*)d_in[12];
  const float* v_att  = (const float*)d_in[13];
  const float* W1     = (const float*)d_in[14];
  const float* b1     = (const float*)d_in[15];
  const float* W2     = (const float*)d_in[16];
  const float* b2     = (const float*)d_in[17];

  char* ws = (char*)d_ws;
  size_t off = 0;
  auto carve = [&](size_t bytes) { char* p = ws + off; off += (bytes + 255) & ~(size_t)255; return p; };
  unsigned short* seq    = (unsigned short*)carve((size_t)T_STEPS * BATCH * LSTMIN * 2);  // 59.0 MB
  unsigned short* xp     = (unsigned short*)carve((size_t)T_STEPS * GATES * BATCH * 2);   // 52.4 MB (reused L0/L1)
  unsigned short* h1     = (unsigned short*)carve((size_t)T_STEPS * BATCH * HIDD * 2);    // 13.1 MB
  unsigned short* h2     = (unsigned short*)carve((size_t)T_STEPS * BATCH * HIDD * 2);    // 13.1 MB
  float*          scores = (float*)carve((size_t)T_STEPS * BATCH * 4);
  unsigned short* wih0b  = (unsigned short*)carve((size_t)GATES * LSTMIN * 2);
  unsigned short* whh0b  = (unsigned short*)carve((size_t)GATES * HIDD * 2);
  unsigned short* wih1b  = (unsigned short*)carve((size_t)GATES * HIDD * 2);
  unsigned short* whh1b  = (unsigned short*)carve((size_t)GATES * HIDD * 2);
  unsigned short* wattb  = (unsigned short*)carve((size_t)HIDD * HIDD * 2);
  float*          convwt = (float*)carve(3200 * 4);
  float*          bias0  = (float*)carve(GATES * 4);
  float*          bias1  = (float*)carve(GATES * 4);

  prep_kernel<<<256, 256, 0, stream>>>(Wih0, Whh0, Wih1, Whh1, W_att, conv_w,
                                       bih0, bhh0, bih1, bhh1,
                                       wih0b, whh0b, wih1b, whh1b, wattb, convwt, bias0, bias1);
  conv_kernel<<<dim3(512, 4), 256, 0, stream>>>(x, convwt, conv_b, seq);
  gemm_xp_kernel<LSTMIN><<<dim3(4, 400), 256, 0, stream>>>(seq, wih0b, bias0, xp);
  scan_kernel<<<32, 512, 0, stream>>>(xp, whh0b, h1);
  gemm_xp_kernel<HIDD><<<dim3(4, 400), 256, 0, stream>>>(h1, wih1b, bias1, xp);
  scan_kernel<<<32, 512, 0, stream>>>(xp, whh1b, h2);
  gemm_att_kernel<<<dim3(1, 400), 256, 0, stream>>>(h2, wattb, b_att, v_att, scores);
  final_kernel<<<512, 128, 0, stream>>>(scores, h2, W1, b1, W2, b2, (float*)d_out);
}

// Round 4
// 500.838 us; speedup vs baseline: 1.2450x; 1.0156x over previous
//
#include <hip/hip_runtime.h>
#include <stdint.h>

// ---------------------------------------------------------------------------
// SpeechResModel forward: conv(1->32,k(20,5),s(8,2))+ReLU -> 2-layer LSTM(576->128->128)
// -> additive attention pooling over T=100 -> FC 128->64->12.
// R4: R3 with f16x2 typedef fixed to __fp16 element type (cvt_pkrtz/fdot2 ABI).
// (1) scan: double-buffered h LDS -> ONE barrier/step; (2) layer-1 x-proj
// fused into scan0; (3) conv via packed f16 v_dot2.
// ---------------------------------------------------------------------------

#define T_STEPS 100
#define BATCH   512
#define HIDD    128
#define GATES   512
#define LSTMIN  576
#define HIMG    812
#define WIMG    40

typedef __attribute__((ext_vector_type(8))) short bf16x8;
typedef __attribute__((ext_vector_type(4))) float f32x4;
typedef __attribute__((ext_vector_type(2))) __fp16 f16x2;

__device__ inline unsigned short f2bf(float f) {
  unsigned u = __float_as_uint(f);
  unsigned r = (u + 0x7fffu + ((u >> 16) & 1u)) >> 16;
  return (unsigned short)r;
}
__device__ inline float bf2f(unsigned short b) {
  return __uint_as_float(((unsigned)b) << 16);
}
__device__ inline float fsigm(float x) {
  float e = __expf(-x);
  return __builtin_amdgcn_rcpf(1.f + e);
}
__device__ inline float ftanh(float x) {
  float e = __expf(2.f * x);
  return (e - 1.f) * __builtin_amdgcn_rcpf(e + 1.f);
}
// LDS-only barrier: does NOT drain vmcnt, so in-flight global prefetches
// survive across it (unlike __syncthreads, which emits vmcnt(0)).
__device__ inline void lds_barrier() {
  asm volatile("s_waitcnt lgkmcnt(0)" ::: "memory");
  __builtin_amdgcn_s_barrier();
}

// ---------------------------------------------------------------------------
// K0: weight prep — bf16 casts, W_att transpose, conv weight kh-pair f16 pack,
// bias sums. Re-run every launch (ws re-poisoned by harness).
// ---------------------------------------------------------------------------
__global__ void prep_kernel(const float* __restrict__ Wih0, const float* __restrict__ Whh0,
                            const float* __restrict__ Wih1, const float* __restrict__ Whh1,
                            const float* __restrict__ Watt, const float* __restrict__ convw,
                            const float* __restrict__ bih0, const float* __restrict__ bhh0,
                            const float* __restrict__ bih1, const float* __restrict__ bhh1,
                            unsigned short* __restrict__ wih0b, unsigned short* __restrict__ whh0b,
                            unsigned short* __restrict__ wih1b, unsigned short* __restrict__ whh1b,
                            unsigned short* __restrict__ wattb, f16x2* __restrict__ wpair,
                            float* __restrict__ bias0, float* __restrict__ bias1) {
  int tid = blockIdx.x * blockDim.x + threadIdx.x;
  int stride = gridDim.x * blockDim.x;
  for (int i = tid; i < GATES * LSTMIN; i += stride) wih0b[i] = f2bf(Wih0[i]);
  for (int i = tid; i < GATES * HIDD; i += stride) whh0b[i] = f2bf(Whh0[i]);
  for (int i = tid; i < GATES * HIDD; i += stride) wih1b[i] = f2bf(Wih1[i]);
  for (int i = tid; i < GATES * HIDD; i += stride) whh1b[i] = f2bf(Whh1[i]);
  // wattb[j][k] = Watt[k][j]  (einsum 'tbh,hk->tbk' -> B^T layout)
  for (int i = tid; i < HIDD * HIDD; i += stride) {
    int j = i >> 7, k = i & 127;
    wattb[i] = f2bf(Watt[k * HIDD + j]);
  }
  // wpair[(kh2*5+kw)*32 + c] = (convw[c][2kh2][kw], convw[c][2kh2+1][kw]) as f16x2
  for (int i = tid; i < 50 * 32; i += stride) {
    int k2 = i >> 5, c = i & 31;
    int kh2 = k2 / 5, kw = k2 % 5;
    float lo = convw[c * 100 + (2 * kh2) * 5 + kw];
    float hi = convw[c * 100 + (2 * kh2 + 1) * 5 + kw];
    wpair[i] = __builtin_amdgcn_cvt_pkrtz(lo, hi);
  }
  for (int i = tid; i < GATES; i += stride) bias0[i] = bih0[i] + bhh0[i];
  for (int i = tid; i < GATES; i += stride) bias1[i] = bih1[i] + bhh1[i];
}

// ---------------------------------------------------------------------------
// K1: conv + ReLU + transpose to seq[t][b][w'*32+c] (bf16), f16 dot2 math.
// Image staged as f16x2 vertical (kh) pairs — kh windows start at even rows
// (8t), so all 10 pairs per window are aligned.
// ---------------------------------------------------------------------------
__global__ __launch_bounds__(256) void conv_kernel(const float* __restrict__ x,
                                                   const f16x2* __restrict__ wpair,
                                                   const float* __restrict__ convb,
                                                   unsigned short* __restrict__ seq) {
  __shared__ f16x2 imgp[106 * WIMG];   // vertical pairs of the 212-row strip
  const int b = blockIdx.x;
  const int chunk = blockIdx.y;        // 0..3
  const int t0 = chunk * 25;
  const float* src = x + (size_t)b * (HIMG * WIMG) + (size_t)(8 * t0) * WIMG;
  for (int i = threadIdx.x; i < 106 * WIMG; i += 256) {
    int r2 = i / WIMG, c = i % WIMG;
    float lo = src[(2 * r2) * WIMG + c];
    float hi = src[(2 * r2 + 1) * WIMG + c];
    imgp[i] = __builtin_amdgcn_cvt_pkrtz(lo, hi);
  }
  __syncthreads();
  for (int p = threadIdx.x; p < 450; p += 256) {
    int tl = p / 18, wp = p % 18;
    int t = t0 + tl;
    float acc[32];
#pragma unroll
    for (int c = 0; c < 32; ++c) acc[c] = 0.f;
    const f16x2* ibase = imgp + (4 * tl) * WIMG + 2 * wp;
#pragma unroll 2
    for (int kh2 = 0; kh2 < 10; ++kh2) {
#pragma unroll
      for (int kw = 0; kw < 5; ++kw) {
        f16x2 iv = ibase[kh2 * WIMG + kw];
        const f16x2* wk = wpair + (kh2 * 5 + kw) * 32;  // uniform -> s_load
#pragma unroll
        for (int c = 0; c < 32; ++c)
          acc[c] = __builtin_amdgcn_fdot2(iv, wk[c], acc[c], false);
      }
    }
    unsigned short* o = seq + ((size_t)(t * BATCH + b)) * LSTMIN + wp * 32;
#pragma unroll
    for (int c = 0; c < 32; ++c) {
      float v = acc[c] + convb[c];
      o[c] = f2bf(v > 0.f ? v : 0.f);
    }
  }
}

// ---------------------------------------------------------------------------
// K2: bf16 MFMA GEMM: C[m][n] = sum_k A[m][k]*Bw[n][k] + bias[n], output in
// scan-native layout (tiles of 256 shorts: [((t*32+blk)*8+w)*4+nt][col16][r16]).
// ---------------------------------------------------------------------------
template <int KDIM>
__global__ __launch_bounds__(256) void gemm_xp_kernel(const unsigned short* __restrict__ A,
                                                      const unsigned short* __restrict__ Bw,
                                                      const float* __restrict__ bias,
                                                      unsigned short* __restrict__ Xp) {
  __shared__ __align__(16) unsigned short As[128 * 32];
  __shared__ __align__(16) unsigned short Bs[128 * 32];
  const int tid = threadIdx.x;
  const int lane = tid & 63;
  const int w = tid >> 6;
  const int col16 = lane & 15;
  const int q = lane >> 4;
  const int n0 = blockIdx.x * 128;
  const int m0 = blockIdx.y * 128;
  const int wm = (w & 1) * 64;
  const int wn = (w >> 1) * 64;
  f32x4 acc[4][4] = {};
  const int r = tid >> 2;
  const int sw = ((tid & 3) ^ (r & 3)) * 8;           // swizzled k-group
  const unsigned wslot = (unsigned)w * 512;
  const unsigned short* ga = A + (size_t)(m0 + r) * KDIM + sw;
  const unsigned short* gb = Bw + (size_t)(n0 + r) * KDIM + sw;
  for (int k0 = 0; k0 < KDIM; k0 += 32) {
    __syncthreads();
    __builtin_amdgcn_global_load_lds((const __attribute__((address_space(1))) void*)(ga + k0),
                                     (__attribute__((address_space(3))) void*)(As + wslot), 16, 0, 0);
    __builtin_amdgcn_global_load_lds((const __attribute__((address_space(1))) void*)(ga + k0 + (size_t)64 * KDIM),
                                     (__attribute__((address_space(3))) void*)(As + wslot + 2048), 16, 0, 0);
    __builtin_amdgcn_global_load_lds((const __attribute__((address_space(1))) void*)(gb + k0),
                                     (__attribute__((address_space(3))) void*)(Bs + wslot), 16, 0, 0);
    __builtin_amdgcn_global_load_lds((const __attribute__((address_space(1))) void*)(gb + k0 + (size_t)64 * KDIM),
                                     (__attribute__((address_space(3))) void*)(Bs + wslot + 2048), 16, 0, 0);
    __syncthreads();  // drains vmcnt(0): LDS tiles valid
    bf16x8 af[4], bv[4];
#pragma unroll
    for (int i = 0; i < 4; ++i) {
      int ra = wm + i * 16 + col16;
      af[i] = *(const bf16x8*)(As + ra * 32 + ((q ^ (ra & 3)) * 8));
      int rb2 = wn + i * 16 + col16;
      bv[i] = *(const bf16x8*)(Bs + rb2 * 32 + ((q ^ (rb2 & 3)) * 8));
    }
#pragma unroll
    for (int i = 0; i < 4; ++i)
#pragma unroll
      for (int j = 0; j < 4; ++j)
        acc[i][j] = __builtin_amdgcn_mfma_f32_16x16x32_bf16(af[i], bv[j], acc[i][j], 0, 0, 0);
  }
#pragma unroll
  for (int ct = 0; ct < 4; ++ct) {
    int n = n0 + wn + ct * 16 + col16;
    float bvv = bias[n];
    int wS = (n >> 4) & 7;
    int ntS = n >> 7;
    int c16S = n & 15;
#pragma unroll
    for (int rt = 0; rt < 4; ++rt) {
      int m = m0 + wm + rt * 16 + q * 4;
      int t = m >> 9;
      int bb = m & 511;
      int blk = bb >> 4;
      int r16 = bb & 15;
      ushort4 u;
      u.x = f2bf(acc[rt][ct][0] + bvv);
      u.y = f2bf(acc[rt][ct][1] + bvv);
      u.z = f2bf(acc[rt][ct][2] + bvv);
      u.w = f2bf(acc[rt][ct][3] + bvv);
      size_t tile = (((size_t)t * 32 + blk) * 8 + wS) * 4 + ntS;
      *(ushort4*)(Xp + tile * 256 + c16S * 16 + r16) = u;
    }
  }
}

// ---------------------------------------------------------------------------
// K3: LSTM scan. 32 blocks x 16 batch rows, 8 waves. Double-buffered h in LDS
// -> ONE lgkm-only barrier per step. FUSE_XP: also computes next layer's input
// projection (Wih1 @ h) with 16 extra MFMAs and stores Xp_out in scan-native
// layout (gemm<128> + h1 array eliminated). WRITE_H: streams h to global
// (readback of step t-1's buffer overlaps step t's MFMAs).
// ---------------------------------------------------------------------------
template <bool FUSE_XP, bool WRITE_H>
__global__ __launch_bounds__(512, 2) void scan_kernel(const unsigned short* __restrict__ Xp,
                                                      const unsigned short* __restrict__ Whh,
                                                      const unsigned short* __restrict__ Wih_n,
                                                      const float* __restrict__ bias_n,
                                                      unsigned short* __restrict__ Xp_out,
                                                      unsigned short* __restrict__ hout) {
  __shared__ __align__(16) unsigned short hb[2][16 * 136];  // padded stride 136
  const int tid = threadIdx.x;
  const int lane = tid & 63;
  const int w = tid >> 6;          // 0..7
  const int col16 = lane & 15;
  const int q = lane >> 4;
  const int rb = blockIdx.x * 16;
  const int blk = blockIdx.x;

  // B-fragments: nt = gate, col cn = nt*128 + w*16 + col16
  bf16x8 bfrag[4][4];
  bf16x8 bfrag2[4][4];
  const unsigned short* xpb[4];
  unsigned short* xob[4];
  float biasn[4];
#pragma unroll
  for (int nt = 0; nt < 4; ++nt) {
    int cn = nt * HIDD + w * 16 + col16;
#pragma unroll
    for (int ks = 0; ks < 4; ++ks)
      bfrag[nt][ks] = *(const bf16x8*)(Whh + (size_t)cn * HIDD + ks * 32 + q * 8);
    if (FUSE_XP) {
#pragma unroll
      for (int ks = 0; ks < 4; ++ks)
        bfrag2[nt][ks] = *(const bf16x8*)(Wih_n + (size_t)cn * HIDD + ks * 32 + q * 8);
      biasn[nt] = bias_n[cn];
    }
    size_t tile = (((size_t)blk) * 8 + w) * 4 + nt;
    xpb[nt] = Xp + tile * 256 + col16 * 16 + q * 4;
    if (FUSE_XP) xob[nt] = Xp_out + tile * 256 + col16 * 16 + q * 4;
  }
  // 2-slot Xp register pipeline (prefetch distance 2, slot reused after consume)
  uint2 xb[2][4];
#pragma unroll
  for (int nt = 0; nt < 4; ++nt) xb[0][nt] = *(const uint2*)(xpb[nt]);
#pragma unroll
  for (int nt = 0; nt < 4; ++nt) xb[1][nt] = *(const uint2*)(xpb[nt] + GATES * BATCH);
  for (int i = tid; i < 2 * 16 * 136; i += 512) hb[0][i] = 0;
  float cst[4] = {0.f, 0.f, 0.f, 0.f};
  lds_barrier();

  const int srow = tid >> 5;           // 0..15 (h readback row)
  const int scol = (tid & 31) * 4;     // 0..124
  const int hc = w * 16 + col16;

#pragma unroll 2
  for (int t = 0; t < T_STEPS; ++t) {
    const int pb = (t & 1) ^ 1;        // buffer holding h(t-1)
    // read A-fragments of h(t-1)
    bf16x8 af[4];
#pragma unroll
    for (int ks = 0; ks < 4; ++ks)
      af[ks] = *(const bf16x8*)(hb[pb] + col16 * 136 + ks * 32 + q * 8);
    // stream h(t-1) to global (overlaps MFMAs below)
    if (WRITE_H && t > 0) {
      ushort4 hx = *(const ushort4*)(hb[pb] + srow * 136 + scol);
      *(ushort4*)(hout + ((size_t)((t - 1) * BATCH) + rb + srow) * HIDD + scol) = hx;
    }
    // consume Xp slot, then refill it for t+2
    const int s = t & 1;
    uint2 xv[4];
#pragma unroll
    for (int nt = 0; nt < 4; ++nt) xv[nt] = xb[s][nt];
    if (t + 2 < T_STEPS) {
#pragma unroll
      for (int nt = 0; nt < 4; ++nt)
        xb[s][nt] = *(const uint2*)(xpb[nt] + (size_t)(t + 2) * (GATES * BATCH));
    }
    f32x4 acc[4];
#pragma unroll
    for (int nt = 0; nt < 4; ++nt) {
      acc[nt][0] = __uint_as_float(xv[nt].x << 16);
      acc[nt][1] = __uint_as_float(xv[nt].x & 0xffff0000u);
      acc[nt][2] = __uint_as_float(xv[nt].y << 16);
      acc[nt][3] = __uint_as_float(xv[nt].y & 0xffff0000u);
    }
#pragma unroll
    for (int ks = 0; ks < 4; ++ks)
#pragma unroll
      for (int nt = 0; nt < 4; ++nt)
        acc[nt] = __builtin_amdgcn_mfma_f32_16x16x32_bf16(af[ks], bfrag[nt][ks], acc[nt], 0, 0, 0);
    f32x4 acc2[4];
    if (FUSE_XP) {
#pragma unroll
      for (int nt = 0; nt < 4; ++nt) acc2[nt] = f32x4{0.f, 0.f, 0.f, 0.f};
#pragma unroll
      for (int ks = 0; ks < 4; ++ks)
#pragma unroll
        for (int nt = 0; nt < 4; ++nt)
          acc2[nt] = __builtin_amdgcn_mfma_f32_16x16x32_bf16(af[ks], bfrag2[nt][ks], acc2[nt], 0, 0, 0);
    }
    unsigned short hv[4];
#pragma unroll
    for (int rr = 0; rr < 4; ++rr) {
      float pi = acc[0][rr], pf = acc[1][rr];
      float pg = acc[2][rr], po = acc[3][rr];
      float cc = fsigm(pf) * cst[rr] + fsigm(pi) * ftanh(pg);
      cst[rr] = cc;
      hv[rr] = f2bf(fsigm(po) * ftanh(cc));
    }
    if (FUSE_XP) {
      // acc2 is the projection of h(t-1) -> Xp_out timestep t-1.
      if (t > 0) {
#pragma unroll
        for (int nt = 0; nt < 4; ++nt) {
          ushort4 u;
          u.x = f2bf(acc2[nt][0] + biasn[nt]);
          u.y = f2bf(acc2[nt][1] + biasn[nt]);
          u.z = f2bf(acc2[nt][2] + biasn[nt]);
          u.w = f2bf(acc2[nt][3] + biasn[nt]);
          *(ushort4*)(xob[nt] + (size_t)(t - 1) * (GATES * BATCH)) = u;
        }
      }
    }
    // write h(t)
#pragma unroll
    for (int rr = 0; rr < 4; ++rr)
      hb[t & 1][(q * 4 + rr) * 136 + hc] = hv[rr];
    lds_barrier();
  }
  // epilogue: last h / last fused projection (uses h(T-1) now in hb[(T-1)&1])
  if (WRITE_H) {
    ushort4 hx = *(const ushort4*)(hb[(T_STEPS - 1) & 1] + srow * 136 + scol);
    *(ushort4*)(hout + ((size_t)((T_STEPS - 1) * BATCH) + rb + srow) * HIDD + scol) = hx;
  }
  if (FUSE_XP) {
    bf16x8 af[4];
#pragma unroll
    for (int ks = 0; ks < 4; ++ks)
      af[ks] = *(const bf16x8*)(hb[(T_STEPS - 1) & 1] + col16 * 136 + ks * 32 + q * 8);
    f32x4 acc2[4];
#pragma unroll
    for (int nt = 0; nt < 4; ++nt) acc2[nt] = f32x4{0.f, 0.f, 0.f, 0.f};
#pragma unroll
    for (int ks = 0; ks < 4; ++ks)
#pragma unroll
      for (int nt = 0; nt < 4; ++nt)
        acc2[nt] = __builtin_amdgcn_mfma_f32_16x16x32_bf16(af[ks], bfrag2[nt][ks], acc2[nt], 0, 0, 0);
#pragma unroll
    for (int nt = 0; nt < 4; ++nt) {
      ushort4 u;
      u.x = f2bf(acc2[nt][0] + biasn[nt]);
      u.y = f2bf(acc2[nt][1] + biasn[nt]);
      u.z = f2bf(acc2[nt][2] + biasn[nt]);
      u.w = f2bf(acc2[nt][3] + biasn[nt]);
      *(ushort4*)(xob[nt] + (size_t)(T_STEPS - 1) * (GATES * BATCH)) = u;
    }
  }
}

// ---------------------------------------------------------------------------
// K4: attention scores: s[m] = v . tanh(h2[m] @ W_att + b_att).
// ---------------------------------------------------------------------------
__global__ __launch_bounds__(256) void gemm_att_kernel(const unsigned short* __restrict__ A,
                                                       const unsigned short* __restrict__ Bw,
                                                       const float* __restrict__ b_att,
                                                       const float* __restrict__ v_att,
                                                       float* __restrict__ scores) {
  __shared__ __align__(16) unsigned short As[128 * 32];
  __shared__ __align__(16) unsigned short Bs[128 * 32];
  __shared__ float s_red[128];
  const int tid = threadIdx.x;
  const int lane = tid & 63;
  const int w = tid >> 6;
  const int col16 = lane & 15;
  const int q = lane >> 4;
  const int m0 = blockIdx.y * 128;
  const int wm = (w & 1) * 64;
  const int wn = (w >> 1) * 64;
  f32x4 acc[4][4] = {};
  const int r = tid >> 2;
  const int sw = ((tid & 3) ^ (r & 3)) * 8;
  const unsigned wslot = (unsigned)w * 512;
  const unsigned short* ga = A + (size_t)(m0 + r) * HIDD + sw;
  const unsigned short* gb = Bw + (size_t)r * HIDD + sw;
  for (int k0 = 0; k0 < HIDD; k0 += 32) {
    __syncthreads();
    __builtin_amdgcn_global_load_lds((const __attribute__((address_space(1))) void*)(ga + k0),
                                     (__attribute__((address_space(3))) void*)(As + wslot), 16, 0, 0);
    __builtin_amdgcn_global_load_lds((const __attribute__((address_space(1))) void*)(ga + k0 + (size_t)64 * HIDD),
                                     (__attribute__((address_space(3))) void*)(As + wslot + 2048), 16, 0, 0);
    __builtin_amdgcn_global_load_lds((const __attribute__((address_space(1))) void*)(gb + k0),
                                     (__attribute__((address_space(3))) void*)(Bs + wslot), 16, 0, 0);
    __builtin_amdgcn_global_load_lds((const __attribute__((address_space(1))) void*)(gb + k0 + (size_t)64 * HIDD),
                                     (__attribute__((address_space(3))) void*)(Bs + wslot + 2048), 16, 0, 0);
    __syncthreads();
    bf16x8 af[4], bv[4];
#pragma unroll
    for (int i = 0; i < 4; ++i) {
      int ra = wm + i * 16 + col16;
      af[i] = *(const bf16x8*)(As + ra * 32 + ((q ^ (ra & 3)) * 8));
      int rb2 = wn + i * 16 + col16;
      bv[i] = *(const bf16x8*)(Bs + rb2 * 32 + ((q ^ (rb2 & 3)) * 8));
    }
#pragma unroll
    for (int i = 0; i < 4; ++i)
#pragma unroll
      for (int j = 0; j < 4; ++j)
        acc[i][j] = __builtin_amdgcn_mfma_f32_16x16x32_bf16(af[i], bv[j], acc[i][j], 0, 0, 0);
  }
  if (tid < 128) s_red[tid] = 0.f;
  float rs[4][4];
#pragma unroll
  for (int rt = 0; rt < 4; ++rt)
#pragma unroll
    for (int rr = 0; rr < 4; ++rr) rs[rt][rr] = 0.f;
#pragma unroll
  for (int ct = 0; ct < 4; ++ct) {
    int n = wn + ct * 16 + col16;
    float bvv = b_att[n], vv = v_att[n];
#pragma unroll
    for (int rt = 0; rt < 4; ++rt)
#pragma unroll
      for (int rr = 0; rr < 4; ++rr) {
        float xv2 = acc[rt][ct][rr] + bvv;
        float e = __expf(2.f * xv2);
        rs[rt][rr] += vv * (e - 1.f) * __builtin_amdgcn_rcpf(e + 1.f);
      }
  }
#pragma unroll
  for (int off = 1; off < 16; off <<= 1)
#pragma unroll
    for (int rt = 0; rt < 4; ++rt)
#pragma unroll
      for (int rr = 0; rr < 4; ++rr) rs[rt][rr] += __shfl_xor(rs[rt][rr], off, 64);
  __syncthreads();
  if (col16 == 0) {
#pragma unroll
    for (int rt = 0; rt < 4; ++rt)
#pragma unroll
      for (int rr = 0; rr < 4; ++rr)
        atomicAdd(&s_red[wm + rt * 16 + q * 4 + rr], rs[rt][rr]);
  }
  __syncthreads();
  if (tid < 128) scores[m0 + tid] = s_red[tid];
}

// ---------------------------------------------------------------------------
// K5: per-batch softmax over T, attention pooling, FC 128->64->12.
// ---------------------------------------------------------------------------
__global__ __launch_bounds__(128) void final_kernel(const float* __restrict__ scores,
                                                    const unsigned short* __restrict__ h2,
                                                    const float* __restrict__ W1, const float* __restrict__ b1,
                                                    const float* __restrict__ W2, const float* __restrict__ b2,
                                                    float* __restrict__ out) {
  const int b = blockIdx.x;
  const int tid = threadIdx.x;
  __shared__ float wj[T_STEPS];
  __shared__ float red[128];
  __shared__ float pooled[128];
  __shared__ float hdn[64];
  float sv = (tid < T_STEPS) ? scores[tid * BATCH + b] : -1e30f;
  red[tid] = sv;
  __syncthreads();
#pragma unroll
  for (int off = 64; off > 0; off >>= 1) {
    if (tid < off) red[tid] = fmaxf(red[tid], red[tid + off]);
    __syncthreads();
  }
  float mx = red[0];
  __syncthreads();
  float ev = (tid < T_STEPS) ? __expf(sv - mx) : 0.f;
  red[tid] = ev;
  __syncthreads();
#pragma unroll
  for (int off = 64; off > 0; off >>= 1) {
    if (tid < off) red[tid] += red[tid + off];
    __syncthreads();
  }
  float inv = 1.0f / red[0];
  if (tid < T_STEPS) wj[tid] = ev * inv;
  __syncthreads();
  float p = 0.f;
  for (int t = 0; t < T_STEPS; ++t)
    p += wj[t] * bf2f(h2[((size_t)(t * BATCH + b)) * HIDD + tid]);
  pooled[tid] = p;
  __syncthreads();
  if (tid < 64) {
    float a = b1[tid];
    for (int h = 0; h < 128; ++h) a = fmaf(W1[tid * 128 + h], pooled[h], a);
    hdn[tid] = a;
  }
  __syncthreads();
  if (tid < 12) {
    float a = b2[tid];
    for (int j = 0; j < 64; ++j) a = fmaf(W2[tid * 64 + j], hdn[j], a);
    out[b * 12 + tid] = a;
  }
}

// ---------------------------------------------------------------------------
extern "C" void kernel_launch(void* const* d_in, const int* in_sizes, int n_in,
                              void* d_out, int out_size, void* d_ws, size_t ws_size,
                              hipStream_t stream) {
  (void)in_sizes; (void)n_in; (void)out_size; (void)ws_size;
  const float* x      = (const float*)d_in[0];
  const float* conv_w = (const float*)d_in[1];
  const float* conv_b = (const float*)d_in[2];
  const float* Wih0   = (const float*)d_in[3];
  const float* Whh0   = (const float*)d_in[4];
  const float* bih0   = (const float*)d_in[5];
  const float* bhh0   = (const float*)d_in[6];
  const float* Wih1   = (const float*)d_in[7];
  const float* Whh1   = (const float*)d_in[8];
  const float* bih1   = (const float*)d_in[9];
  const float* bhh1   = (const float*)d_in[10];
  const float* W_att  = (const float*)d_in[11];
  const float* b_att  = (const float*)d_in[12];
  const float* v_att  = (const float*)d_in[13];
  const float* W1     = (const float*)d_in[14];
  const float* b1     = (const float*)d_in[15];
  const float* W2     = (const float*)d_in[16];
  const float* b2     = (const float*)d_in[17];

  char* ws = (char*)d_ws;
  size_t off = 0;
  auto carve = [&](size_t bytes) { char* p = ws + off; off += (bytes + 255) & ~(size_t)255; return p; };
  unsigned short* seq    = (unsigned short*)carve((size_t)T_STEPS * BATCH * LSTMIN * 2);  // 59.0 MB; reused as xp1
  unsigned short* xp0    = (unsigned short*)carve((size_t)T_STEPS * GATES * BATCH * 2);   // 52.4 MB
  unsigned short* h2     = (unsigned short*)carve((size_t)T_STEPS * BATCH * HIDD * 2);    // 13.1 MB
  float*          scores = (float*)carve((size_t)T_STEPS * BATCH * 4);
  unsigned short* wih0b  = (unsigned short*)carve((size_t)GATES * LSTMIN * 2);
  unsigned short* whh0b  = (unsigned short*)carve((size_t)GATES * HIDD * 2);
  unsigned short* wih1b  = (unsigned short*)carve((size_t)GATES * HIDD * 2);
  unsigned short* whh1b  = (unsigned short*)carve((size_t)GATES * HIDD * 2);
  unsigned short* wattb  = (unsigned short*)carve((size_t)HIDD * HIDD * 2);
  f16x2*          wpair  = (f16x2*)carve(50 * 32 * 4);
  float*          bias0  = (float*)carve(GATES * 4);
  float*          bias1  = (float*)carve(GATES * 4);
  unsigned short* xp1 = seq;  // seq is dead after gemm<576>; scan0 writes xp1 over it

  prep_kernel<<<256, 256, 0, stream>>>(Wih0, Whh0, Wih1, Whh1, W_att, conv_w,
                                       bih0, bhh0, bih1, bhh1,
                                       wih0b, whh0b, wih1b, whh1b, wattb, wpair, bias0, bias1);
  conv_kernel<<<dim3(512, 4), 256, 0, stream>>>(x, wpair, conv_b, seq);
  gemm_xp_kernel<LSTMIN><<<dim3(4, 400), 256, 0, stream>>>(seq, wih0b, bias0, xp0);
  scan_kernel<true, false><<<32, 512, 0, stream>>>(xp0, whh0b, wih1b, bias1, xp1, nullptr);
  scan_kernel<false, true><<<32, 512, 0, stream>>>(xp1, whh1b, nullptr, nullptr, nullptr, h2);
  gemm_att_kernel<<<dim3(1, 400), 256, 0, stream>>>(h2, wattb, b_att, v_att, scores);
  final_kernel<<<512, 128, 0, stream>>>(scores, h2, W1, b1, W2, b2, (float*)d_out);
}

// Round 5
// 412.500 us; speedup vs baseline: 1.5116x; 1.2142x over previous
//
#include <hip/hip_runtime.h>
#include <stdint.h>

// ---------------------------------------------------------------------------
// SpeechResModel forward: conv(1->32,k(20,5),s(8,2))+ReLU -> 2-layer LSTM(576->128->128)
// -> additive attention pooling over T=100 -> FC 128->64->12.
// R5: the two LSTM scans run CONCURRENTLY in one 64-block dispatch.
// Blocks 0-31: layer-0 scan with fused Wih1 projection -> Xp1 (producer).
// Blocks 32-63: layer-1 scan consuming Xp1 (consumer), gated by per-pair
// flags with agent-scope release/acquire (cross-XCD correct). Cadence 4 steps.
// ---------------------------------------------------------------------------

#define T_STEPS 100
#define BATCH   512
#define HIDD    128
#define GATES   512
#define LSTMIN  576
#define HIMG    812
#define WIMG    40

typedef __attribute__((ext_vector_type(8))) short bf16x8;
typedef __attribute__((ext_vector_type(4))) float f32x4;
typedef __attribute__((ext_vector_type(2))) __fp16 f16x2;

__device__ inline unsigned short f2bf(float f) {
  unsigned u = __float_as_uint(f);
  unsigned r = (u + 0x7fffu + ((u >> 16) & 1u)) >> 16;
  return (unsigned short)r;
}
__device__ inline float bf2f(unsigned short b) {
  return __uint_as_float(((unsigned)b) << 16);
}
__device__ inline float fsigm(float x) {
  float e = __expf(-x);
  return __builtin_amdgcn_rcpf(1.f + e);
}
__device__ inline float ftanh(float x) {
  float e = __expf(2.f * x);
  return (e - 1.f) * __builtin_amdgcn_rcpf(e + 1.f);
}
// LDS-only barrier: does NOT drain vmcnt (global prefetches stay in flight).
__device__ inline void lds_barrier() {
  asm volatile("s_waitcnt lgkmcnt(0)" ::: "memory");
  __builtin_amdgcn_s_barrier();
}
// Full drain barrier: vmcnt(0) so all global stores are in L2 before release.
__device__ inline void full_barrier() {
  asm volatile("s_waitcnt vmcnt(0) lgkmcnt(0)" ::: "memory");
  __builtin_amdgcn_s_barrier();
}
// Per-wave spin until *fp >= need (acquire: invalidates L1/L2 so subsequent
// loads see the producer's flushed data).
__device__ inline void wait_flag(const int* fp, int need) {
  if ((threadIdx.x & 63) == 0) {
    int v = __hip_atomic_load(fp, __ATOMIC_ACQUIRE, __HIP_MEMORY_SCOPE_AGENT);
    while (v < need) {
      __builtin_amdgcn_s_sleep(2);
      v = __hip_atomic_load(fp, __ATOMIC_ACQUIRE, __HIP_MEMORY_SCOPE_AGENT);
    }
  }
}

// ---------------------------------------------------------------------------
// K0: weight prep — bf16 casts, W_att transpose, conv f16 pair pack, bias sums,
// pipeline flag zeroing. Re-run every launch (ws re-poisoned by harness).
// ---------------------------------------------------------------------------
__global__ void prep_kernel(const float* __restrict__ Wih0, const float* __restrict__ Whh0,
                            const float* __restrict__ Wih1, const float* __restrict__ Whh1,
                            const float* __restrict__ Watt, const float* __restrict__ convw,
                            const float* __restrict__ bih0, const float* __restrict__ bhh0,
                            const float* __restrict__ bih1, const float* __restrict__ bhh1,
                            unsigned short* __restrict__ wih0b, unsigned short* __restrict__ whh0b,
                            unsigned short* __restrict__ wih1b, unsigned short* __restrict__ whh1b,
                            unsigned short* __restrict__ wattb, f16x2* __restrict__ wpair,
                            float* __restrict__ bias0, float* __restrict__ bias1,
                            int* __restrict__ flags) {
  int tid = blockIdx.x * blockDim.x + threadIdx.x;
  int stride = gridDim.x * blockDim.x;
  for (int i = tid; i < GATES * LSTMIN; i += stride) wih0b[i] = f2bf(Wih0[i]);
  for (int i = tid; i < GATES * HIDD; i += stride) whh0b[i] = f2bf(Whh0[i]);
  for (int i = tid; i < GATES * HIDD; i += stride) wih1b[i] = f2bf(Wih1[i]);
  for (int i = tid; i < GATES * HIDD; i += stride) whh1b[i] = f2bf(Whh1[i]);
  for (int i = tid; i < HIDD * HIDD; i += stride) {
    int j = i >> 7, k = i & 127;
    wattb[i] = f2bf(Watt[k * HIDD + j]);
  }
  for (int i = tid; i < 50 * 32; i += stride) {
    int k2 = i >> 5, c = i & 31;
    int kh2 = k2 / 5, kw = k2 % 5;
    float lo = convw[c * 100 + (2 * kh2) * 5 + kw];
    float hi = convw[c * 100 + (2 * kh2 + 1) * 5 + kw];
    wpair[i] = __builtin_amdgcn_cvt_pkrtz(lo, hi);
  }
  for (int i = tid; i < GATES; i += stride) bias0[i] = bih0[i] + bhh0[i];
  for (int i = tid; i < GATES; i += stride) bias1[i] = bih1[i] + bhh1[i];
  for (int i = tid; i < 32; i += stride) flags[i] = 0;
}

// ---------------------------------------------------------------------------
// K1: conv + ReLU + transpose to seq[t][b][w'*32+c] (bf16), f16 dot2 math.
// ---------------------------------------------------------------------------
__global__ __launch_bounds__(256) void conv_kernel(const float* __restrict__ x,
                                                   const f16x2* __restrict__ wpair,
                                                   const float* __restrict__ convb,
                                                   unsigned short* __restrict__ seq) {
  __shared__ f16x2 imgp[106 * WIMG];
  const int b = blockIdx.x;
  const int chunk = blockIdx.y;
  const int t0 = chunk * 25;
  const float* src = x + (size_t)b * (HIMG * WIMG) + (size_t)(8 * t0) * WIMG;
  for (int i = threadIdx.x; i < 106 * WIMG; i += 256) {
    int r2 = i / WIMG, c = i % WIMG;
    float lo = src[(2 * r2) * WIMG + c];
    float hi = src[(2 * r2 + 1) * WIMG + c];
    imgp[i] = __builtin_amdgcn_cvt_pkrtz(lo, hi);
  }
  __syncthreads();
  for (int p = threadIdx.x; p < 450; p += 256) {
    int tl = p / 18, wp = p % 18;
    int t = t0 + tl;
    float acc[32];
#pragma unroll
    for (int c = 0; c < 32; ++c) acc[c] = 0.f;
    const f16x2* ibase = imgp + (4 * tl) * WIMG + 2 * wp;
#pragma unroll 2
    for (int kh2 = 0; kh2 < 10; ++kh2) {
#pragma unroll
      for (int kw = 0; kw < 5; ++kw) {
        f16x2 iv = ibase[kh2 * WIMG + kw];
        const f16x2* wk = wpair + (kh2 * 5 + kw) * 32;
#pragma unroll
        for (int c = 0; c < 32; ++c)
          acc[c] = __builtin_amdgcn_fdot2(iv, wk[c], acc[c], false);
      }
    }
    unsigned short* o = seq + ((size_t)(t * BATCH + b)) * LSTMIN + wp * 32;
#pragma unroll
    for (int c = 0; c < 32; ++c) {
      float v = acc[c] + convb[c];
      o[c] = f2bf(v > 0.f ? v : 0.f);
    }
  }
}

// ---------------------------------------------------------------------------
// K2: bf16 MFMA GEMM -> Xp0 in scan-native layout.
// ---------------------------------------------------------------------------
template <int KDIM>
__global__ __launch_bounds__(256) void gemm_xp_kernel(const unsigned short* __restrict__ A,
                                                      const unsigned short* __restrict__ Bw,
                                                      const float* __restrict__ bias,
                                                      unsigned short* __restrict__ Xp) {
  __shared__ __align__(16) unsigned short As[128 * 32];
  __shared__ __align__(16) unsigned short Bs[128 * 32];
  const int tid = threadIdx.x;
  const int lane = tid & 63;
  const int w = tid >> 6;
  const int col16 = lane & 15;
  const int q = lane >> 4;
  const int n0 = blockIdx.x * 128;
  const int m0 = blockIdx.y * 128;
  const int wm = (w & 1) * 64;
  const int wn = (w >> 1) * 64;
  f32x4 acc[4][4] = {};
  const int r = tid >> 2;
  const int sw = ((tid & 3) ^ (r & 3)) * 8;
  const unsigned wslot = (unsigned)w * 512;
  const unsigned short* ga = A + (size_t)(m0 + r) * KDIM + sw;
  const unsigned short* gb = Bw + (size_t)(n0 + r) * KDIM + sw;
  for (int k0 = 0; k0 < KDIM; k0 += 32) {
    __syncthreads();
    __builtin_amdgcn_global_load_lds((const __attribute__((address_space(1))) void*)(ga + k0),
                                     (__attribute__((address_space(3))) void*)(As + wslot), 16, 0, 0);
    __builtin_amdgcn_global_load_lds((const __attribute__((address_space(1))) void*)(ga + k0 + (size_t)64 * KDIM),
                                     (__attribute__((address_space(3))) void*)(As + wslot + 2048), 16, 0, 0);
    __builtin_amdgcn_global_load_lds((const __attribute__((address_space(1))) void*)(gb + k0),
                                     (__attribute__((address_space(3))) void*)(Bs + wslot), 16, 0, 0);
    __builtin_amdgcn_global_load_lds((const __attribute__((address_space(1))) void*)(gb + k0 + (size_t)64 * KDIM),
                                     (__attribute__((address_space(3))) void*)(Bs + wslot + 2048), 16, 0, 0);
    __syncthreads();
    bf16x8 af[4], bv[4];
#pragma unroll
    for (int i = 0; i < 4; ++i) {
      int ra = wm + i * 16 + col16;
      af[i] = *(const bf16x8*)(As + ra * 32 + ((q ^ (ra & 3)) * 8));
      int rb2 = wn + i * 16 + col16;
      bv[i] = *(const bf16x8*)(Bs + rb2 * 32 + ((q ^ (rb2 & 3)) * 8));
    }
#pragma unroll
    for (int i = 0; i < 4; ++i)
#pragma unroll
      for (int j = 0; j < 4; ++j)
        acc[i][j] = __builtin_amdgcn_mfma_f32_16x16x32_bf16(af[i], bv[j], acc[i][j], 0, 0, 0);
  }
#pragma unroll
  for (int ct = 0; ct < 4; ++ct) {
    int n = n0 + wn + ct * 16 + col16;
    float bvv = bias[n];
    int wS = (n >> 4) & 7;
    int ntS = n >> 7;
    int c16S = n & 15;
#pragma unroll
    for (int rt = 0; rt < 4; ++rt) {
      int m = m0 + wm + rt * 16 + q * 4;
      int t = m >> 9;
      int bb = m & 511;
      int blk = bb >> 4;
      int r16 = bb & 15;
      ushort4 u;
      u.x = f2bf(acc[rt][ct][0] + bvv);
      u.y = f2bf(acc[rt][ct][1] + bvv);
      u.z = f2bf(acc[rt][ct][2] + bvv);
      u.w = f2bf(acc[rt][ct][3] + bvv);
      size_t tile = (((size_t)t * 32 + blk) * 8 + wS) * 4 + ntS;
      *(ushort4*)(Xp + tile * 256 + c16S * 16 + r16) = u;
    }
  }
}

// ---------------------------------------------------------------------------
// K3: PIPELINED two-layer LSTM scan. 64 blocks, 512 threads.
// blocks 0-31 = producer (layer 0, fused Wih1 projection -> Xp1, flag release
// every 4 steps); blocks 32-63 = consumer (layer 1, flag-gated Xp1 reads,
// writes h2). Pair i/i+32 handles batch slice i. Math identical to R4.
// ---------------------------------------------------------------------------
__global__ __launch_bounds__(512, 2) void scan_pipe_kernel(
    const unsigned short* __restrict__ Xp0, const unsigned short* __restrict__ Whh0,
    const unsigned short* __restrict__ Wih1, const float* __restrict__ bias1,
    unsigned short* __restrict__ Xp1, const unsigned short* __restrict__ Whh1,
    unsigned short* __restrict__ hout, int* __restrict__ flags) {
  __shared__ __align__(16) unsigned short hb[2][16 * 136];
  const int tid = threadIdx.x;
  const int lane = tid & 63;
  const int w = tid >> 6;
  const int col16 = lane & 15;
  const int q = lane >> 4;
  const bool producer = blockIdx.x < 32;
  const int blk = producer ? (int)blockIdx.x : (int)blockIdx.x - 32;
  const int rb = blk * 16;
  const int hc = w * 16 + col16;
  const int srow = tid >> 5;
  const int scol = (tid & 31) * 4;
  int* flagp = flags + blk;

  if (producer) {
    // ---------------- layer 0: scan + fused Wih1 projection ----------------
    bf16x8 bfrag[4][4], bfrag2[4][4];
    const unsigned short* xpb[4];
    unsigned short* xob[4];
    float biasn[4];
#pragma unroll
    for (int nt = 0; nt < 4; ++nt) {
      int cn = nt * HIDD + hc;
#pragma unroll
      for (int ks = 0; ks < 4; ++ks) {
        bfrag[nt][ks] = *(const bf16x8*)(Whh0 + (size_t)cn * HIDD + ks * 32 + q * 8);
        bfrag2[nt][ks] = *(const bf16x8*)(Wih1 + (size_t)cn * HIDD + ks * 32 + q * 8);
      }
      biasn[nt] = bias1[cn];
      size_t tile = (((size_t)blk) * 8 + w) * 4 + nt;
      xpb[nt] = Xp0 + tile * 256 + col16 * 16 + q * 4;
      xob[nt] = Xp1 + tile * 256 + col16 * 16 + q * 4;
    }
    uint2 xb[2][4];
#pragma unroll
    for (int nt = 0; nt < 4; ++nt) xb[0][nt] = *(const uint2*)(xpb[nt]);
#pragma unroll
    for (int nt = 0; nt < 4; ++nt) xb[1][nt] = *(const uint2*)(xpb[nt] + GATES * BATCH);
    for (int i = tid; i < 2 * 16 * 136; i += 512) hb[0][i] = 0;
    float cst[4] = {0.f, 0.f, 0.f, 0.f};
    lds_barrier();

#pragma unroll 4
    for (int t = 0; t < T_STEPS; ++t) {
      const int pb = (t & 1) ^ 1;
      bf16x8 af[4];
#pragma unroll
      for (int ks = 0; ks < 4; ++ks)
        af[ks] = *(const bf16x8*)(hb[pb] + col16 * 136 + ks * 32 + q * 8);
      const int s = t & 1;
      uint2 xv[4];
#pragma unroll
      for (int nt = 0; nt < 4; ++nt) xv[nt] = xb[s][nt];
      if (t + 2 < T_STEPS) {
#pragma unroll
        for (int nt = 0; nt < 4; ++nt)
          xb[s][nt] = *(const uint2*)(xpb[nt] + (size_t)(t + 2) * (GATES * BATCH));
      }
      f32x4 acc[4];
#pragma unroll
      for (int nt = 0; nt < 4; ++nt) {
        acc[nt][0] = __uint_as_float(xv[nt].x << 16);
        acc[nt][1] = __uint_as_float(xv[nt].x & 0xffff0000u);
        acc[nt][2] = __uint_as_float(xv[nt].y << 16);
        acc[nt][3] = __uint_as_float(xv[nt].y & 0xffff0000u);
      }
#pragma unroll
      for (int ks = 0; ks < 4; ++ks)
#pragma unroll
        for (int nt = 0; nt < 4; ++nt)
          acc[nt] = __builtin_amdgcn_mfma_f32_16x16x32_bf16(af[ks], bfrag[nt][ks], acc[nt], 0, 0, 0);
      f32x4 acc2[4];
#pragma unroll
      for (int nt = 0; nt < 4; ++nt) acc2[nt] = f32x4{0.f, 0.f, 0.f, 0.f};
#pragma unroll
      for (int ks = 0; ks < 4; ++ks)
#pragma unroll
        for (int nt = 0; nt < 4; ++nt)
          acc2[nt] = __builtin_amdgcn_mfma_f32_16x16x32_bf16(af[ks], bfrag2[nt][ks], acc2[nt], 0, 0, 0);
      unsigned short hv[4];
#pragma unroll
      for (int rr = 0; rr < 4; ++rr) {
        float pi = acc[0][rr], pf = acc[1][rr];
        float pg = acc[2][rr], po = acc[3][rr];
        float cc = fsigm(pf) * cst[rr] + fsigm(pi) * ftanh(pg);
        cst[rr] = cc;
        hv[rr] = f2bf(fsigm(po) * ftanh(cc));
      }
      if (t > 0) {
        // acc2 = Wih1 @ h(t-1) -> Xp1[t-1]
#pragma unroll
        for (int nt = 0; nt < 4; ++nt) {
          ushort4 u;
          u.x = f2bf(acc2[nt][0] + biasn[nt]);
          u.y = f2bf(acc2[nt][1] + biasn[nt]);
          u.z = f2bf(acc2[nt][2] + biasn[nt]);
          u.w = f2bf(acc2[nt][3] + biasn[nt]);
          *(ushort4*)(xob[nt] + (size_t)(t - 1) * (GATES * BATCH)) = u;
        }
      }
#pragma unroll
      for (int rr = 0; rr < 4; ++rr)
        hb[t & 1][(q * 4 + rr) * 136 + hc] = hv[rr];
      if ((t & 3) == 3) {
        full_barrier();  // all waves' Xp1 stores (indices <= t-1) drained to L2
        if (tid == 0)
          __hip_atomic_store(flagp, t, __ATOMIC_RELEASE, __HIP_MEMORY_SCOPE_AGENT);
      } else {
        lds_barrier();
      }
    }
    // epilogue: Xp1[99] from h(99)
    bf16x8 af[4];
#pragma unroll
    for (int ks = 0; ks < 4; ++ks)
      af[ks] = *(const bf16x8*)(hb[(T_STEPS - 1) & 1] + col16 * 136 + ks * 32 + q * 8);
    f32x4 acc2[4];
#pragma unroll
    for (int nt = 0; nt < 4; ++nt) acc2[nt] = f32x4{0.f, 0.f, 0.f, 0.f};
#pragma unroll
    for (int ks = 0; ks < 4; ++ks)
#pragma unroll
      for (int nt = 0; nt < 4; ++nt)
        acc2[nt] = __builtin_amdgcn_mfma_f32_16x16x32_bf16(af[ks], bfrag2[nt][ks], acc2[nt], 0, 0, 0);
#pragma unroll
    for (int nt = 0; nt < 4; ++nt) {
      ushort4 u;
      u.x = f2bf(acc2[nt][0] + biasn[nt]);
      u.y = f2bf(acc2[nt][1] + biasn[nt]);
      u.z = f2bf(acc2[nt][2] + biasn[nt]);
      u.w = f2bf(acc2[nt][3] + biasn[nt]);
      *(ushort4*)(xob[nt] + (size_t)(T_STEPS - 1) * (GATES * BATCH)) = u;
    }
    full_barrier();
    if (tid == 0)
      __hip_atomic_store(flagp, 100, __ATOMIC_RELEASE, __HIP_MEMORY_SCOPE_AGENT);
  } else {
    // ---------------- layer 1: flag-gated scan, writes h2 ----------------
    bf16x8 bfrag[4][4];
    const unsigned short* xpb[4];
#pragma unroll
    for (int nt = 0; nt < 4; ++nt) {
      int cn = nt * HIDD + hc;
#pragma unroll
      for (int ks = 0; ks < 4; ++ks)
        bfrag[nt][ks] = *(const bf16x8*)(Whh1 + (size_t)cn * HIDD + ks * 32 + q * 8);
      size_t tile = (((size_t)blk) * 8 + w) * 4 + nt;
      xpb[nt] = Xp1 + tile * 256 + col16 * 16 + q * 4;
    }
    for (int i = tid; i < 2 * 16 * 136; i += 512) hb[0][i] = 0;
    wait_flag(flagp, 6);  // covers preload {0,1} and first group's prefetch {2..5}
    uint2 xb[2][4];
#pragma unroll
    for (int nt = 0; nt < 4; ++nt) xb[0][nt] = *(const uint2*)(xpb[nt]);
#pragma unroll
    for (int nt = 0; nt < 4; ++nt) xb[1][nt] = *(const uint2*)(xpb[nt] + GATES * BATCH);
    float cst[4] = {0.f, 0.f, 0.f, 0.f};
    lds_barrier();

#pragma unroll 4
    for (int t = 0; t < T_STEPS; ++t) {
      if (t > 0 && (t & 3) == 0) {
        int need = t + 6;
        if (need > 100) need = 100;
        wait_flag(flagp, need);  // covers this group's prefetches {t+2..t+5}
      }
      const int pb = (t & 1) ^ 1;
      bf16x8 af[4];
#pragma unroll
      for (int ks = 0; ks < 4; ++ks)
        af[ks] = *(const bf16x8*)(hb[pb] + col16 * 136 + ks * 32 + q * 8);
      if (t > 0) {
        ushort4 hx = *(const ushort4*)(hb[pb] + srow * 136 + scol);
        *(ushort4*)(hout + ((size_t)((t - 1) * BATCH) + rb + srow) * HIDD + scol) = hx;
      }
      const int s = t & 1;
      uint2 xv[4];
#pragma unroll
      for (int nt = 0; nt < 4; ++nt) xv[nt] = xb[s][nt];
      if (t + 2 < T_STEPS) {
#pragma unroll
        for (int nt = 0; nt < 4; ++nt)
          xb[s][nt] = *(const uint2*)(xpb[nt] + (size_t)(t + 2) * (GATES * BATCH));
      }
      f32x4 acc[4];
#pragma unroll
      for (int nt = 0; nt < 4; ++nt) {
        acc[nt][0] = __uint_as_float(xv[nt].x << 16);
        acc[nt][1] = __uint_as_float(xv[nt].x & 0xffff0000u);
        acc[nt][2] = __uint_as_float(xv[nt].y << 16);
        acc[nt][3] = __uint_as_float(xv[nt].y & 0xffff0000u);
      }
#pragma unroll
      for (int ks = 0; ks < 4; ++ks)
#pragma unroll
        for (int nt = 0; nt < 4; ++nt)
          acc[nt] = __builtin_amdgcn_mfma_f32_16x16x32_bf16(af[ks], bfrag[nt][ks], acc[nt], 0, 0, 0);
      unsigned short hv[4];
#pragma unroll
      for (int rr = 0; rr < 4; ++rr) {
        float pi = acc[0][rr], pf = acc[1][rr];
        float pg = acc[2][rr], po = acc[3][rr];
        float cc = fsigm(pf) * cst[rr] + fsigm(pi) * ftanh(pg);
        cst[rr] = cc;
        hv[rr] = f2bf(fsigm(po) * ftanh(cc));
      }
#pragma unroll
      for (int rr = 0; rr < 4; ++rr)
        hb[t & 1][(q * 4 + rr) * 136 + hc] = hv[rr];
      lds_barrier();
    }
    ushort4 hx = *(const ushort4*)(hb[(T_STEPS - 1) & 1] + srow * 136 + scol);
    *(ushort4*)(hout + ((size_t)((T_STEPS - 1) * BATCH) + rb + srow) * HIDD + scol) = hx;
  }
}

// ---------------------------------------------------------------------------
// K4: attention scores: s[m] = v . tanh(h2[m] @ W_att + b_att).
// ---------------------------------------------------------------------------
__global__ __launch_bounds__(256) void gemm_att_kernel(const unsigned short* __restrict__ A,
                                                       const unsigned short* __restrict__ Bw,
                                                       const float* __restrict__ b_att,
                                                       const float* __restrict__ v_att,
                                                       float* __restrict__ scores) {
  __shared__ __align__(16) unsigned short As[128 * 32];
  __shared__ __align__(16) unsigned short Bs[128 * 32];
  __shared__ float s_red[128];
  const int tid = threadIdx.x;
  const int lane = tid & 63;
  const int w = tid >> 6;
  const int col16 = lane & 15;
  const int q = lane >> 4;
  const int m0 = blockIdx.y * 128;
  const int wm = (w & 1) * 64;
  const int wn = (w >> 1) * 64;
  f32x4 acc[4][4] = {};
  const int r = tid >> 2;
  const int sw = ((tid & 3) ^ (r & 3)) * 8;
  const unsigned wslot = (unsigned)w * 512;
  const unsigned short* ga = A + (size_t)(m0 + r) * HIDD + sw;
  const unsigned short* gb = Bw + (size_t)r * HIDD + sw;
  for (int k0 = 0; k0 < HIDD; k0 += 32) {
    __syncthreads();
    __builtin_amdgcn_global_load_lds((const __attribute__((address_space(1))) void*)(ga + k0),
                                     (__attribute__((address_space(3))) void*)(As + wslot), 16, 0, 0);
    __builtin_amdgcn_global_load_lds((const __attribute__((address_space(1))) void*)(ga + k0 + (size_t)64 * HIDD),
                                     (__attribute__((address_space(3))) void*)(As + wslot + 2048), 16, 0, 0);
    __builtin_amdgcn_global_load_lds((const __attribute__((address_space(1))) void*)(gb + k0),
                                     (__attribute__((address_space(3))) void*)(Bs + wslot), 16, 0, 0);
    __builtin_amdgcn_global_load_lds((const __attribute__((address_space(1))) void*)(gb + k0 + (size_t)64 * HIDD),
                                     (__attribute__((address_space(3))) void*)(Bs + wslot + 2048), 16, 0, 0);
    __syncthreads();
    bf16x8 af[4], bv[4];
#pragma unroll
    for (int i = 0; i < 4; ++i) {
      int ra = wm + i * 16 + col16;
      af[i] = *(const bf16x8*)(As + ra * 32 + ((q ^ (ra & 3)) * 8));
      int rb2 = wn + i * 16 + col16;
      bv[i] = *(const bf16x8*)(Bs + rb2 * 32 + ((q ^ (rb2 & 3)) * 8));
    }
#pragma unroll
    for (int i = 0; i < 4; ++i)
#pragma unroll
      for (int j = 0; j < 4; ++j)
        acc[i][j] = __builtin_amdgcn_mfma_f32_16x16x32_bf16(af[i], bv[j], acc[i][j], 0, 0, 0);
  }
  if (tid < 128) s_red[tid] = 0.f;
  float rs[4][4];
#pragma unroll
  for (int rt = 0; rt < 4; ++rt)
#pragma unroll
    for (int rr = 0; rr < 4; ++rr) rs[rt][rr] = 0.f;
#pragma unroll
  for (int ct = 0; ct < 4; ++ct) {
    int n = wn + ct * 16 + col16;
    float bvv = b_att[n], vv = v_att[n];
#pragma unroll
    for (int rt = 0; rt < 4; ++rt)
#pragma unroll
      for (int rr = 0; rr < 4; ++rr) {
        float xv2 = acc[rt][ct][rr] + bvv;
        float e = __expf(2.f * xv2);
        rs[rt][rr] += vv * (e - 1.f) * __builtin_amdgcn_rcpf(e + 1.f);
      }
  }
#pragma unroll
  for (int off = 1; off < 16; off <<= 1)
#pragma unroll
    for (int rt = 0; rt < 4; ++rt)
#pragma unroll
      for (int rr = 0; rr < 4; ++rr) rs[rt][rr] += __shfl_xor(rs[rt][rr], off, 64);
  __syncthreads();
  if (col16 == 0) {
#pragma unroll
    for (int rt = 0; rt < 4; ++rt)
#pragma unroll
      for (int rr = 0; rr < 4; ++rr)
        atomicAdd(&s_red[wm + rt * 16 + q * 4 + rr], rs[rt][rr]);
  }
  __syncthreads();
  if (tid < 128) scores[m0 + tid] = s_red[tid];
}

// ---------------------------------------------------------------------------
// K5: per-batch softmax over T, attention pooling, FC 128->64->12.
// ---------------------------------------------------------------------------
__global__ __launch_bounds__(128) void final_kernel(const float* __restrict__ scores,
                                                    const unsigned short* __restrict__ h2,
                                                    const float* __restrict__ W1, const float* __restrict__ b1,
                                                    const float* __restrict__ W2, const float* __restrict__ b2,
                                                    float* __restrict__ out) {
  const int b = blockIdx.x;
  const int tid = threadIdx.x;
  __shared__ float wj[T_STEPS];
  __shared__ float red[128];
  __shared__ float pooled[128];
  __shared__ float hdn[64];
  float sv = (tid < T_STEPS) ? scores[tid * BATCH + b] : -1e30f;
  red[tid] = sv;
  __syncthreads();
#pragma unroll
  for (int off = 64; off > 0; off >>= 1) {
    if (tid < off) red[tid] = fmaxf(red[tid], red[tid + off]);
    __syncthreads();
  }
  float mx = red[0];
  __syncthreads();
  float ev = (tid < T_STEPS) ? __expf(sv - mx) : 0.f;
  red[tid] = ev;
  __syncthreads();
#pragma unroll
  for (int off = 64; off > 0; off >>= 1) {
    if (tid < off) red[tid] += red[tid + off];
    __syncthreads();
  }
  float inv = 1.0f / red[0];
  if (tid < T_STEPS) wj[tid] = ev * inv;
  __syncthreads();
  float p = 0.f;
  for (int t = 0; t < T_STEPS; ++t)
    p += wj[t] * bf2f(h2[((size_t)(t * BATCH + b)) * HIDD + tid]);
  pooled[tid] = p;
  __syncthreads();
  if (tid < 64) {
    float a = b1[tid];
    for (int h = 0; h < 128; ++h) a = fmaf(W1[tid * 128 + h], pooled[h], a);
    hdn[tid] = a;
  }
  __syncthreads();
  if (tid < 12) {
    float a = b2[tid];
    for (int j = 0; j < 64; ++j) a = fmaf(W2[tid * 64 + j], hdn[j], a);
    out[b * 12 + tid] = a;
  }
}

// ---------------------------------------------------------------------------
extern "C" void kernel_launch(void* const* d_in, const int* in_sizes, int n_in,
                              void* d_out, int out_size, void* d_ws, size_t ws_size,
                              hipStream_t stream) {
  (void)in_sizes; (void)n_in; (void)out_size; (void)ws_size;
  const float* x      = (const float*)d_in[0];
  const float* conv_w = (const float*)d_in[1];
  const float* conv_b = (const float*)d_in[2];
  const float* Wih0   = (const float*)d_in[3];
  const float* Whh0   = (const float*)d_in[4];
  const float* bih0   = (const float*)d_in[5];
  const float* bhh0   = (const float*)d_in[6];
  const float* Wih1   = (const float*)d_in[7];
  const float* Whh1   = (const float*)d_in[8];
  const float* bih1   = (const float*)d_in[9];
  const float* bhh1   = (const float*)d_in[10];
  const float* W_att  = (const float*)d_in[11];
  const float* b_att  = (const float*)d_in[12];
  const float* v_att  = (const float*)d_in[13];
  const float* W1     = (const float*)d_in[14];
  const float* b1     = (const float*)d_in[15];
  const float* W2     = (const float*)d_in[16];
  const float* b2     = (const float*)d_in[17];

  char* ws = (char*)d_ws;
  size_t off = 0;
  auto carve = [&](size_t bytes) { char* p = ws + off; off += (bytes + 255) & ~(size_t)255; return p; };
  unsigned short* seq    = (unsigned short*)carve((size_t)T_STEPS * BATCH * LSTMIN * 2);  // reused as xp1
  unsigned short* xp0    = (unsigned short*)carve((size_t)T_STEPS * GATES * BATCH * 2);
  unsigned short* h2     = (unsigned short*)carve((size_t)T_STEPS * BATCH * HIDD * 2);
  float*          scores = (float*)carve((size_t)T_STEPS * BATCH * 4);
  unsigned short* wih0b  = (unsigned short*)carve((size_t)GATES * LSTMIN * 2);
  unsigned short* whh0b  = (unsigned short*)carve((size_t)GATES * HIDD * 2);
  unsigned short* wih1b  = (unsigned short*)carve((size_t)GATES * HIDD * 2);
  unsigned short* whh1b  = (unsigned short*)carve((size_t)GATES * HIDD * 2);
  unsigned short* wattb  = (unsigned short*)carve((size_t)HIDD * HIDD * 2);
  f16x2*          wpair  = (f16x2*)carve(50 * 32 * 4);
  float*          bias0  = (float*)carve(GATES * 4);
  float*          bias1  = (float*)carve(GATES * 4);
  int*            flags  = (int*)carve(32 * 4);
  unsigned short* xp1 = seq;  // seq dead after gemm<576>; producer writes xp1 over it

  prep_kernel<<<256, 256, 0, stream>>>(Wih0, Whh0, Wih1, Whh1, W_att, conv_w,
                                       bih0, bhh0, bih1, bhh1,
                                       wih0b, whh0b, wih1b, whh1b, wattb, wpair,
                                       bias0, bias1, flags);
  conv_kernel<<<dim3(512, 4), 256, 0, stream>>>(x, wpair, conv_b, seq);
  gemm_xp_kernel<LSTMIN><<<dim3(4, 400), 256, 0, stream>>>(seq, wih0b, bias0, xp0);
  scan_pipe_kernel<<<64, 512, 0, stream>>>(xp0, whh0b, wih1b, bias1, xp1, whh1b, h2, flags);
  gemm_att_kernel<<<dim3(1, 400), 256, 0, stream>>>(h2, wattb, b_att, v_att, scores);
  final_kernel<<<512, 128, 0, stream>>>(scores, h2, W1, b1, W2, b2, (float*)d_out);
}